// Round 4
// baseline (760.922 us; speedup 1.0000x reference)
//
#include <hip/hip_runtime.h>

#define NN 50000
#define EE 800000
#define FHID 128
#define NHEAD 4
#define NGRAPH 512
#define NCLS 10
#define BK 256            // buckets (dst>>8)
#define BCH 2048          // edges per block in bin kernel (391 blocks)
#define NBLK_E 391        // ceil(EE/BCH)
#define NBUCK 196         // ceil(NN/256)
#define CAPB 6144         // slack capacity per bucket (mean 4096, 32-sigma headroom)

typedef unsigned short u16;
typedef unsigned int u32;
typedef unsigned long long u64;
typedef __attribute__((ext_vector_type(8))) short bf16x8;
typedef __attribute__((ext_vector_type(4))) float f32x4;

__device__ __forceinline__ float bf2f(u16 u){
    union { u32 i; float f; } v; v.i = ((u32)u) << 16; return v.f;
}
__device__ __forceinline__ float bflo(u32 u){
    union { u32 i; float f; } v; v.i = u << 16; return v.f;
}
__device__ __forceinline__ float bfhi(u32 u){
    union { u32 i; float f; } v; v.i = u & 0xffff0000u; return v.f;
}
__device__ __forceinline__ u16 f2bf(float f){
    union { float f; u32 i; } v; v.f = f;
    u32 r = v.i + 0x7fffu + ((v.i >> 16) & 1u);
    return (u16)(r >> 16);
}
__device__ __forceinline__ u32 pack2(float a, float b){
    return ((u32)f2bf(b) << 16) | f2bf(a);
}
__device__ __forceinline__ float loadF(const void* p, int i, int isf32){
    return isf32 ? ((const float*)p)[i] : bf2f(((const u16*)p)[i]);
}
__device__ __forceinline__ void unpk8(uint4 v, float* f){
    f[0]=bflo(v.x); f[1]=bfhi(v.x);
    f[2]=bflo(v.y); f[3]=bfhi(v.y);
    f[4]=bflo(v.z); f[5]=bfhi(v.z);
    f[6]=bflo(v.w); f[7]=bfhi(v.w);
}

// 4-lane (quad) butterfly reduce in the VALU pipe via DPP quad_perm.
// Quads are always exec-uniform here (4 lanes of a quad share a head of one node).
__device__ __forceinline__ float quad_red(float x){
    int t0 = __builtin_amdgcn_mov_dpp(__float_as_int(x), 0xB1, 0xF, 0xF, true); // [1,0,3,2]
    float y = x + __int_as_float(t0);
    int t1 = __builtin_amdgcn_mov_dpp(__float_as_int(y), 0x4E, 0xF, 0xF, true); // [2,3,0,1]
    return y + __int_as_float(t1);
}

// block-local dtype detect: count bf16-plausible halfwords in x[0..1023] (lds reduce)
__device__ int detect_local(const u16* x, int tid, int nthreads, int* lds){
    int ok = 0;
    for (int i = tid; i < 1024; i += nthreads){
        u16 u = x[i];
        int e = (u >> 7) & 0xFF;
        if ((u & 0x7fff) == 0 || (e >= 0x70 && e <= 0x85)) ok++;
    }
    lds[tid] = ok;
    __syncthreads();
    for (int o2 = nthreads >> 1; o2 > 0; o2 >>= 1){
        if (tid < o2) lds[tid] += lds[tid + o2];
        __syncthreads();
    }
    int r = (lds[0] < 900) ? 1 : 0;   // 1 = f32 inputs
    __syncthreads();
    return r;
}

// ---------------- fused prep: weights (blocks 0..511) + head/att (512..527) ---------
// block 0 also initializes gcur[t] = t*CAPB (slack-bucket bases)
__global__ __launch_bounds__(256) void prep_all(
        const u16* __restrict__ xz,
        const void* w_feat, const void* b_feat, const void* bn_feat_g, const void* bn_feat_b,
        const void* w_gat, const void* bn_conv_g, const void* bn_conv_b, const void* b_gat,
        const void* wfc, const void* bfc, const void* bnfg, const void* bnfb,
        const void* bnhg, const void* bnhb, const void* wcls, const void* bcls,
        const void* attl, const void* attr,
        u16* __restrict__ Wt, float* __restrict__ cvec, float* __restrict__ biasv,
        float* __restrict__ hp, int* __restrict__ dflag, int* __restrict__ gcur)
{
    __shared__ int ldsi[256];
    __shared__ float red[128];
    int bid = blockIdx.x, t = threadIdx.x;
    int isf32 = detect_local(xz, t, 256, ldsi);
    if (bid == 0){
        if (t == 0) dflag[0] = isf32;
        gcur[t] = t * CAPB;
    }

    if (bid < 512){
        if (t >= 128) return;
        int L = bid >> 7;
        int n = bid & 127;
        int k = t;
        const float rs = rsqrtf(1.0f + 1e-5f);
        float wv, bg, bb;
        if (L == 0){
            wv = loadF(w_feat, k*FHID + n, isf32);
            bg = loadF(bn_feat_g, k, isf32);
            bb = loadF(bn_feat_b, k, isf32);
        } else {
            wv = loadF(w_gat, (L-1)*FHID*FHID + k*FHID + n, isf32);
            bg = loadF(bn_conv_g, (L-1)*FHID + k, isf32);
            bb = loadF(bn_conv_b, (L-1)*FHID + k, isf32);
        }
        Wt[L*FHID*FHID + n*FHID + k] = f2bf(bg * rs * wv);
        red[k] = bb * wv;
        __syncthreads();
        for (int o2 = 64; o2 > 0; o2 >>= 1){
            if (k < o2) red[k] += red[k + o2];
            __syncthreads();
        }
        if (k == 0){
            float c = red[0];
            if (L == 0) c += loadF(b_feat, n, isf32);
            cvec[L*FHID + n] = c;
            if (L > 0) biasv[L*FHID + n] = loadF(b_gat, (L-1)*FHID + n, isf32);
        }
    } else {
        int gt = (bid - 512)*256 + t;
        for (int i = gt; i < FHID*FHID; i += 16*256) hp[i] = loadF(wfc, i, isf32);
        if (gt < FHID*NCLS) hp[16384 + gt] = loadF(wcls, gt, isf32);
        if (gt >= 2048 && gt < 2048 + 3*FHID){
            int i = gt - 2048;
            hp[18320 + i] = loadF(attl, i, isf32);
            hp[18704 + i] = loadF(attr, i, isf32);
        }
        if (gt >= 2560 && gt < 2560 + FHID){
            int tt = gt - 2560;
            hp[17664 + tt] = loadF(bnfg, tt, isf32);
            hp[17792 + tt] = loadF(bnfb, tt, isf32);
            hp[17920 + tt] = loadF(bfc,  tt, isf32);
            hp[18048 + tt] = loadF(bnhg, tt, isf32);
            hp[18176 + tt] = loadF(bnhb, tt, isf32);
        }
        if (gt >= 3072 && gt < 3072 + NCLS) hp[18304 + (gt - 3072)] = loadF(bcls, gt - 3072, isf32);
    }
}

// ---------------- MFMA GEMM: swapped operands + fused node_alpha epilogue -----------
// 16 rows/wave: 3125 waves (~3/SIMD) for latency hiding on this small kernel.
__global__ __launch_bounds__(256) void gemm128(const void* __restrict__ A,
                                               const u16* __restrict__ Wt,
                                               const float* __restrict__ cvec,
                                               u16* __restrict__ out, int relu,
                                               int araw, const int* __restrict__ flag,
                                               const float* __restrict__ attl,
                                               const float* __restrict__ attr,
                                               float* __restrict__ al,
                                               float* __restrict__ ar)
{
    int wave = threadIdx.x >> 6;
    int lane = threadIdx.x & 63;
    int m = lane & 15, quad = lane >> 4;
    int row = blockIdx.x * 64 + wave * 16 + m;
    bool v0 = row < NN;
    bool f32in = araw && flag[0];
    const u16*  Au = (const u16*)A;
    const float* Af = (const float*)A;
    f32x4 acc[8];
#pragma unroll
    for (int j = 0; j < 8; j++) acc[j] = (f32x4){0.f,0.f,0.f,0.f};
#pragma unroll
    for (int t = 0; t < 4; t++){
        bf16x8 a0 = {0,0,0,0,0,0,0,0};
        int kof = t*32 + quad*8;
        if (f32in){
            if (v0){
                const float* p = Af + (size_t)row*FHID + kof;
                float4 u0 = *(const float4*)p, u1 = *(const float4*)(p+4);
                a0[0]=(short)f2bf(u0.x); a0[1]=(short)f2bf(u0.y);
                a0[2]=(short)f2bf(u0.z); a0[3]=(short)f2bf(u0.w);
                a0[4]=(short)f2bf(u1.x); a0[5]=(short)f2bf(u1.y);
                a0[6]=(short)f2bf(u1.z); a0[7]=(short)f2bf(u1.w);
            }
        } else {
            if (v0) a0 = *(const bf16x8*)(Au + (size_t)row*FHID + kof);
        }
#pragma unroll
        for (int ct = 0; ct < 8; ct++){
            bf16x8 wfrag = *(const bf16x8*)(Wt + (ct*16 + m)*FHID + kof);
            acc[ct] = __builtin_amdgcn_mfma_f32_16x16x32_bf16(wfrag, a0, acc[ct], 0, 0, 0);
        }
    }
    bool doa = (attl != nullptr);
    float sl[4] = {0.f,0.f,0.f,0.f};
    float sr[4] = {0.f,0.f,0.f,0.f};
#pragma unroll
    for (int ct = 0; ct < 8; ct++){
        int cb = ct*16 + quad*4;
        float4 cv = *(const float4*)(cvec + cb);
        float w0 = acc[ct][0] + cv.x;
        float w1 = acc[ct][1] + cv.y;
        float w2 = acc[ct][2] + cv.z;
        float w3 = acc[ct][3] + cv.w;
        if (relu){
            w0 = fmaxf(w0, 0.f); w1 = fmaxf(w1, 0.f);
            w2 = fmaxf(w2, 0.f); w3 = fmaxf(w3, 0.f);
        }
        if (doa){
            int h = ct >> 1;
            float4 tl = *(const float4*)(attl + cb);
            float4 tr = *(const float4*)(attr + cb);
            sl[h] += w0*tl.x + w1*tl.y + w2*tl.z + w3*tl.w;
            sr[h] += w0*tr.x + w1*tr.y + w2*tr.z + w3*tr.w;
        }
        if (v0){
            uint2 st; st.x = pack2(w0, w1); st.y = pack2(w2, w3);
            *(uint2*)(out + (size_t)row*FHID + cb) = st;
        }
    }
    if (doa){
#pragma unroll
        for (int h = 0; h < 4; h++){
            sl[h] += __shfl_xor(sl[h], 16, 64);
            sl[h] += __shfl_xor(sl[h], 32, 64);
            sr[h] += __shfl_xor(sr[h], 16, 64);
            sr[h] += __shfl_xor(sr[h], 32, 64);
        }
        if (v0){
            al[row*NHEAD + quad] = sl[quad];
            ar[row*NHEAD + quad] = sr[quad];
        }
    }
}

// ---------------- bin edges into slack buckets (no global histogram needed) ---------
__global__ __launch_bounds__(256) void bin_edges(const int* __restrict__ srcp,
        const int* __restrict__ dstp, int* __restrict__ gcur, u64* __restrict__ binned)
{
    __shared__ int h[BK], lb[BK], gb[BK], cur[BK];
    __shared__ u64 stage[BCH];
    int t = threadIdx.x;
    h[t] = 0;
    __syncthreads();
    int base = blockIdx.x * BCH;
    int sv[8], dv[8];
#pragma unroll
    for (int k = 0; k < 8; k++){
        int e = base + k*256 + t;
        int d = -1, s = 0;
        if (e < EE){
            d = dstp[e]; s = srcp[e];
            if ((u32)d >= NN) d = -1;
        }
        sv[k] = s; dv[k] = d;
        if (d >= 0) atomicAdd(&h[d >> 8], 1);
    }
    __syncthreads();
    lb[t] = h[t];
    __syncthreads();
    for (int off = 1; off < BK; off <<= 1){
        int x = (t >= off) ? lb[t - off] : 0;
        __syncthreads();
        lb[t] += x;
        __syncthreads();
    }
    int excl = lb[t] - h[t];
    int tot  = lb[BK-1];
    __syncthreads();
    lb[t] = excl;
    gb[t] = h[t] ? atomicAdd(&gcur[t], h[t]) : 0;
    cur[t] = 0;
    __syncthreads();
#pragma unroll
    for (int k = 0; k < 8; k++){
        int d = dv[k];
        if (d >= 0){
            int b = d >> 8;
            int p = lb[b] + atomicAdd(&cur[b], 1);
            stage[p] = ((u64)(u32)d << 32) | (u32)sv[k];
        }
    }
    __syncthreads();
    for (int i = t; i < tot; i += 256){
        u64 pr = stage[i];
        int b = (int)(pr >> 40);
        binned[gb[b] + (i - lb[b])] = pr;
    }
}

// ---------------- per-bucket CSR: rowdeg int2 {start,end} into slack colbuf ---------
__global__ __launch_bounds__(512) void build_csr(const u64* __restrict__ binned,
        const int* __restrict__ gcur, int2* __restrict__ rowdeg, int* __restrict__ colbuf)
{
    __shared__ int deg[BK], ls[BK], cur[BK];
    __shared__ int colstage[CAPB];
    int b = blockIdx.x, t = threadIdx.x;
    int gb = b * CAPB;
    int cnt = gcur[b] - gb;
    if (cnt < 0) cnt = 0;
    if (cnt > CAPB) cnt = CAPB;
    if (t < BK) deg[t] = 0;
    __syncthreads();
    for (int i = t; i < cnt; i += 512){
        int d = (int)(binned[gb + i] >> 32);
        atomicAdd(&deg[d & 255], 1);
    }
    __syncthreads();
    if (t < BK) ls[t] = deg[t];
    __syncthreads();
    for (int off = 1; off < BK; off <<= 1){
        int x = (t < BK && t >= off) ? ls[t - off] : 0;
        __syncthreads();
        if (t < BK) ls[t] += x;
        __syncthreads();
    }
    if (t < BK){
        int excl = ls[t] - deg[t];
        int node = b*256 + t;
        if (node < NN) rowdeg[node] = (int2){gb + excl, gb + excl + deg[t]};
        cur[t] = excl;
    }
    __syncthreads();
    for (int i = t; i < cnt; i += 512){
        u64 pr = binned[gb + i];
        int d = (int)(pr >> 32) & 255;
        int s = (int)(u32)pr;
        int p = atomicAdd(&cur[d], 1);
        colstage[p] = s;
    }
    __syncthreads();
    for (int i = t; i < cnt; i += 512) colbuf[gb + i] = colstage[i];
}

// ---------------- SuperGAT conv: ONE NODE PER WAVE, depth-3 gather pipeline -------
// 4 lane-groups process 4 edges of the SAME node per iteration (wave-uniform trip).
// Depth-3 rotating pipeline with single-exit CFG: +1 slot (~5 VGPR) over the proven
// depth-2 structure; 12 outstanding row-gathers per wave. Round-3 lesson: depth-4 +
// multi-break CFG exceeded the 64-VGPR cap of __launch_bounds__(256,8) and spilled
// (WRITE_SIZE 12.5 -> 257 MB). Tail handled by wave-uniform masked comps.
__device__ __forceinline__ void load_e(uint4& X, float& F, int e, int e1,
        const int* __restrict__ colbuf, const u16* __restrict__ hh,
        const float* __restrict__ al, int chbase, int head)
{
    int si = colbuf[e];                 // +64-int slack allocated past BK*CAPB
    bool bad = (e >= e1) || ((u32)si >= NN);
    if (bad) si = 0;
    X = *(const uint4*)(hh + (size_t)si*FHID + chbase);
    float f = al[si*NHEAD + head];
    F = bad ? -1e30f : f;               // masked: pe = exp(-huge) == 0 exactly
}

__device__ __forceinline__ void comp_e(uint4 X, float F,
        const float* hd, float arn, float& s, float* o)
{
    float hs[8]; unpk8(X, hs);
    float lg = hd[0]*hs[0]+hd[1]*hs[1]+hd[2]*hs[2]+hd[3]*hs[3]
             + hd[4]*hs[4]+hd[5]*hs[5]+hd[6]*hs[6]+hd[7]*hs[7];
    lg = quad_red(lg);
    float a2 = (F + arn) * (1.0f / (1.0f + __expf(-lg)));
    a2 = fmaxf(a2, 0.2f*a2);            // leaky_relu(a2, 0.2) for all signs
    float pe = __expf(fminf(a2, 60.f));
    s += pe;
#pragma unroll
    for (int i = 0; i < 8; i++) o[i] += pe*hs[i];
}

__global__ __launch_bounds__(256, 8) void supergat_conv(const u16* __restrict__ hh,
        const float* __restrict__ al, const float* __restrict__ ar,
        const int2* __restrict__ rowdeg, const int* __restrict__ colbuf,
        const float* __restrict__ bias, u16* __restrict__ hout)
{
    int node = (blockIdx.x*256 + threadIdx.x) >> 6;     // one wave per node
    int lane = threadIdx.x & 63;
    int group = lane >> 4;
    int gl    = lane & 15;
    int head  = gl >> 2;
    int chbase = head*32 + (gl & 3)*8;
    if (node >= NN) return;                              // wave-uniform

    uint4 hdv = *(const uint4*)(hh + (size_t)node*FHID + chbase);
    float hd[8]; unpk8(hdv, hd);
    float arn = ar[node*NHEAD + head];
    float aln = al[node*NHEAD + head];

    // self-loop term (identical in all groups; count it once via group-0 mask)
    float d = hd[0]*hd[0]+hd[1]*hd[1]+hd[2]*hd[2]+hd[3]*hd[3]
            + hd[4]*hd[4]+hd[5]*hd[5]+hd[6]*hd[6]+hd[7]*hd[7];
    d = quad_red(d);
    float a = (aln + arn) * (1.0f / (1.0f + __expf(-d)));
    a = fmaxf(a, 0.2f*a);
    float p = __expf(fminf(a, 60.f));
    if (group != 0) p = 0.f;
    float s = p;
    float o[8];
#pragma unroll
    for (int i = 0; i < 8; i++) o[i] = p*hd[i];

    int2 rd = rowdeg[node];
    int e0 = rd.x, e1 = rd.y;
    if (e0 < 0) e0 = 0;
    if (e1 > BK*CAPB) e1 = BK*CAPB;
    int rem = (e1 - e0 + 3) >> 2;                        // wave-uniform trip count
    int e = e0 + group;

    if (rem > 0){
        uint4 X0, X1, X2;
        float F0, F1, F2;
        load_e(X0, F0, e,   e1, colbuf, hh, al, chbase, head);
        load_e(X1, F1, e+4, e1, colbuf, hh, al, chbase, head);
        load_e(X2, F2, e+8, e1, colbuf, hh, al, chbase, head);
        e += 12;
        while (rem >= 3){
            comp_e(X0, F0, hd, arn, s, o);
            load_e(X0, F0, e,   e1, colbuf, hh, al, chbase, head);
            comp_e(X1, F1, hd, arn, s, o);
            load_e(X1, F1, e+4, e1, colbuf, hh, al, chbase, head);
            comp_e(X2, F2, hd, arn, s, o);
            load_e(X2, F2, e+8, e1, colbuf, hh, al, chbase, head);
            e += 12; rem -= 3;
        }
        if (rem > 0) comp_e(X0, F0, hd, arn, s, o);      // wave-uniform branches
        if (rem > 1) comp_e(X1, F1, hd, arn, s, o);
    }

    // combine the 4 groups' partials (same channels, disjoint edge subsets)
    s += __shfl_xor(s, 16, 64);
    s += __shfl_xor(s, 32, 64);
#pragma unroll
    for (int i = 0; i < 8; i++){
        o[i] += __shfl_xor(o[i], 16, 64);
        o[i] += __shfl_xor(o[i], 32, 64);
    }

    if (group == 0){
        float inv = 1.0f / (s + 1e-16f);
        uint4 w;
        w.x = pack2(fmaxf(o[0]*inv + bias[chbase+0], 0.f),
                    fmaxf(o[1]*inv + bias[chbase+1], 0.f));
        w.y = pack2(fmaxf(o[2]*inv + bias[chbase+2], 0.f),
                    fmaxf(o[3]*inv + bias[chbase+3], 0.f));
        w.z = pack2(fmaxf(o[4]*inv + bias[chbase+4], 0.f),
                    fmaxf(o[5]*inv + bias[chbase+5], 0.f));
        w.w = pack2(fmaxf(o[6]*inv + bias[chbase+6], 0.f),
                    fmaxf(o[7]*inv + bias[chbase+7], 0.f));
        *(uint4*)(hout + (size_t)node*FHID + chbase) = w;
    }
}

// ---------------- fused pool + head: one block per graph ----------------------------
__global__ void pool_head(const u16* __restrict__ h, const int* __restrict__ batch,
                          const float* __restrict__ hp, const int* __restrict__ flag,
                          void* __restrict__ out)
{
    __shared__ int bounds[2];
    __shared__ float gb[FHID];
    __shared__ float g2[FHID];
    __shared__ float lg[16];
    int gi = blockIdx.x, t = threadIdx.x;
    int isf32 = flag[0];
    if (t < 2){
        int target = gi + t;
        int lo = 0, hi = NN;
        while (lo < hi){
            int mid = (lo + hi) >> 1;
            if (batch[mid] < target) lo = mid + 1; else hi = mid;
        }
        bounds[t] = lo;
    }
    __syncthreads();
    float s0 = 0.f, s1 = 0.f, s2 = 0.f, s3 = 0.f;
    int node = bounds[0], nend = bounds[1];
    for (; node + 3 < nend; node += 4){
        s0 += bf2f(h[(size_t)(node+0)*FHID + t]);
        s1 += bf2f(h[(size_t)(node+1)*FHID + t]);
        s2 += bf2f(h[(size_t)(node+2)*FHID + t]);
        s3 += bf2f(h[(size_t)(node+3)*FHID + t]);
    }
    for (; node < nend; node++) s0 += bf2f(h[(size_t)node*FHID + t]);
    float acc0 = (s0 + s1) + (s2 + s3);
    const float rs = rsqrtf(1.0f + 1e-5f);
    gb[t] = acc0 * (hp[17664 + t] * rs) + hp[17792 + t];
    __syncthreads();
    float acc = hp[17920 + t];
    for (int k = 0; k < FHID; k++) acc += gb[k] * hp[k*FHID + t];
    acc = fmaxf(acc, 0.f);
    g2[t] = acc * (hp[18048 + t] * rs) + hp[18176 + t];
    __syncthreads();
    if (t < NCLS){
        float l = hp[18304 + t];
        for (int k = 0; k < FHID; k++) l += g2[k] * hp[16384 + k*NCLS + t];
        lg[t] = l;
    }
    __syncthreads();
    if (t == 0){
        float mx = lg[0];
        for (int j = 1; j < NCLS; j++) mx = fmaxf(mx, lg[j]);
        float se = 0.f;
        for (int j = 0; j < NCLS; j++) se += __expf(lg[j] - mx);
        float lse = logf(se) + mx;
        if (isf32){
            float* o = (float*)out;
            for (int j = 0; j < NCLS; j++) o[gi*NCLS + j] = lg[j] - lse;
            if (gi == 0) o[NGRAPH*NCLS] = 0.f;
        } else {
            u16* o = (u16*)out;
            for (int j = 0; j < NCLS; j++) o[gi*NCLS + j] = f2bf(lg[j] - lse);
            if (gi == 0) o[NGRAPH*NCLS] = 0;
        }
    }
}

extern "C" void kernel_launch(void* const* d_in, const int* in_sizes, int n_in,
                              void* d_out, int out_size, void* d_ws, size_t ws_size,
                              hipStream_t stream)
{
    (void)in_sizes; (void)n_in; (void)out_size; (void)ws_size;
    const void* x         = d_in[0];
    const int* edge       = (const int*)d_in[1];
    const int* batch      = (const int*)d_in[2];

    char* ws = (char*)d_ws;
    size_t off = 0;
    auto alloc = [&](size_t bytes) -> char* {
        char* p = ws + off; off += (bytes + 255) & ~(size_t)255; return p;
    };
    int*   dflag   = (int*)  alloc(256);
    u16*   WtAll   = (u16*)  alloc((size_t)4*FHID*FHID*2);
    float* cvecAll = (float*)alloc((size_t)4*FHID*4);
    float* biasv   = (float*)alloc((size_t)4*FHID*4);
    float* headp   = (float*)alloc((size_t)19088*4);
    float* al      = (float*)alloc((size_t)NN*NHEAD*4);
    float* ar      = (float*)alloc((size_t)NN*NHEAD*4);
    int*   gcur    = (int*)  alloc((size_t)BK*4);
    int2*  rowdeg  = (int2*) alloc((size_t)NN*8);
    int*   colbuf  = (int*)  alloc((size_t)(BK*CAPB + 64)*4);  // +64 ints: depth-3 pipeline over-read slack
    u16*   hA      = (u16*)  alloc((size_t)NN*FHID*2);
    u16*   hB      = (u16*)  alloc((size_t)NN*FHID*2);
    // binned (256*6144*8 = 12.58 MB) aliases hB (12.8 MB): hB first written by the
    // layer-1 gemm, strictly after build_csr (stream-ordered).
    u64*   binned  = (u64*)hB;

    const int* srcp = edge;
    const int* dstp = edge + EE;

    prep_all<<<528, 256, 0, stream>>>((const u16*)x,
        d_in[5], d_in[6], d_in[3], d_in[4], d_in[9], d_in[7], d_in[8], d_in[12],
        d_in[15], d_in[16], d_in[13], d_in[14], d_in[17], d_in[18], d_in[19], d_in[20],
        d_in[10], d_in[11],
        WtAll, cvecAll, biasv, headp, dflag, gcur);

    bin_edges<<<NBLK_E, 256, 0, stream>>>(srcp, dstp, gcur, binned);
    build_csr<<<NBUCK, 512, 0, stream>>>(binned, gcur, rowdeg, colbuf);

    // feature layer: reads raw x (f32 or bf16 per flag), converts in-register
    gemm128<<<(NN + 63)/64, 256, 0, stream>>>(x, WtAll, cvecAll, hA, 1, 1, dflag,
                                              nullptr, nullptr, nullptr, nullptr);

    for (int i = 0; i < 3; i++){
        gemm128<<<(NN + 63)/64, 256, 0, stream>>>(hA, WtAll + (i+1)*FHID*FHID,
                                                  cvecAll + (i+1)*FHID, hB, 0, 0, dflag,
                                                  headp + 18320 + i*FHID,
                                                  headp + 18704 + i*FHID, al, ar);
        supergat_conv<<<(NN + 3)/4, 256, 0, stream>>>(hB, al, ar, rowdeg, colbuf,
                                                      biasv + (i+1)*FHID, hA);
    }

    pool_head<<<NGRAPH, 128, 0, stream>>>(hA, batch, headp, dflag, d_out);
}

// Round 5
// 400.323 us; speedup vs baseline: 1.9008x; 1.9008x over previous
//
#include <hip/hip_runtime.h>

#define NN 50000
#define EE 800000
#define FHID 128
#define NHEAD 4
#define NGRAPH 512
#define NCLS 10
#define BK 256            // buckets (dst>>8)
#define BCH 2048          // edges per block in bin kernel (391 blocks)
#define NBLK_E 391        // ceil(EE/BCH)
#define NBUCK 196         // ceil(NN/256)
#define CAPB 6144         // slack capacity per bucket (mean 4096, 32-sigma headroom)

typedef unsigned short u16;
typedef unsigned int u32;
typedef unsigned long long u64;
typedef __attribute__((ext_vector_type(8))) short bf16x8;
typedef __attribute__((ext_vector_type(4))) float f32x4;

__device__ __forceinline__ float bf2f(u16 u){
    union { u32 i; float f; } v; v.i = ((u32)u) << 16; return v.f;
}
__device__ __forceinline__ float bflo(u32 u){
    union { u32 i; float f; } v; v.i = u << 16; return v.f;
}
__device__ __forceinline__ float bfhi(u32 u){
    union { u32 i; float f; } v; v.i = u & 0xffff0000u; return v.f;
}
__device__ __forceinline__ u16 f2bf(float f){
    union { float f; u32 i; } v; v.f = f;
    u32 r = v.i + 0x7fffu + ((v.i >> 16) & 1u);
    return (u16)(r >> 16);
}
__device__ __forceinline__ u32 pack2(float a, float b){
    return ((u32)f2bf(b) << 16) | f2bf(a);
}
__device__ __forceinline__ float loadF(const void* p, int i, int isf32){
    return isf32 ? ((const float*)p)[i] : bf2f(((const u16*)p)[i]);
}
__device__ __forceinline__ void unpk8(uint4 v, float* f){
    f[0]=bflo(v.x); f[1]=bfhi(v.x);
    f[2]=bflo(v.y); f[3]=bfhi(v.y);
    f[4]=bflo(v.z); f[5]=bfhi(v.z);
    f[6]=bflo(v.w); f[7]=bfhi(v.w);
}

// 4-lane (quad) butterfly reduce in the VALU pipe via DPP quad_perm.
// Quads are always exec-uniform here (4 lanes of a quad share a head of one node).
__device__ __forceinline__ float quad_red(float x){
    int t0 = __builtin_amdgcn_mov_dpp(__float_as_int(x), 0xB1, 0xF, 0xF, true); // [1,0,3,2]
    float y = x + __int_as_float(t0);
    int t1 = __builtin_amdgcn_mov_dpp(__float_as_int(y), 0x4E, 0xF, 0xF, true); // [2,3,0,1]
    return y + __int_as_float(t1);
}

// block-local dtype detect: count bf16-plausible halfwords in x[0..1023] (lds reduce)
__device__ int detect_local(const u16* x, int tid, int nthreads, int* lds){
    int ok = 0;
    for (int i = tid; i < 1024; i += nthreads){
        u16 u = x[i];
        int e = (u >> 7) & 0xFF;
        if ((u & 0x7fff) == 0 || (e >= 0x70 && e <= 0x85)) ok++;
    }
    lds[tid] = ok;
    __syncthreads();
    for (int o2 = nthreads >> 1; o2 > 0; o2 >>= 1){
        if (tid < o2) lds[tid] += lds[tid + o2];
        __syncthreads();
    }
    int r = (lds[0] < 900) ? 1 : 0;   // 1 = f32 inputs
    __syncthreads();
    return r;
}

// ---------------- fused prep: weights (blocks 0..511) + head/att (512..527) ---------
// block 0 also initializes gcur[t] = t*CAPB (slack-bucket bases)
__global__ __launch_bounds__(256) void prep_all(
        const u16* __restrict__ xz,
        const void* w_feat, const void* b_feat, const void* bn_feat_g, const void* bn_feat_b,
        const void* w_gat, const void* bn_conv_g, const void* bn_conv_b, const void* b_gat,
        const void* wfc, const void* bfc, const void* bnfg, const void* bnfb,
        const void* bnhg, const void* bnhb, const void* wcls, const void* bcls,
        const void* attl, const void* attr,
        u16* __restrict__ Wt, float* __restrict__ cvec, float* __restrict__ biasv,
        float* __restrict__ hp, int* __restrict__ dflag, int* __restrict__ gcur)
{
    __shared__ int ldsi[256];
    __shared__ float red[128];
    int bid = blockIdx.x, t = threadIdx.x;
    int isf32 = detect_local(xz, t, 256, ldsi);
    if (bid == 0){
        if (t == 0) dflag[0] = isf32;
        gcur[t] = t * CAPB;
    }

    if (bid < 512){
        if (t >= 128) return;
        int L = bid >> 7;
        int n = bid & 127;
        int k = t;
        const float rs = rsqrtf(1.0f + 1e-5f);
        float wv, bg, bb;
        if (L == 0){
            wv = loadF(w_feat, k*FHID + n, isf32);
            bg = loadF(bn_feat_g, k, isf32);
            bb = loadF(bn_feat_b, k, isf32);
        } else {
            wv = loadF(w_gat, (L-1)*FHID*FHID + k*FHID + n, isf32);
            bg = loadF(bn_conv_g, (L-1)*FHID + k, isf32);
            bb = loadF(bn_conv_b, (L-1)*FHID + k, isf32);
        }
        Wt[L*FHID*FHID + n*FHID + k] = f2bf(bg * rs * wv);
        red[k] = bb * wv;
        __syncthreads();
        for (int o2 = 64; o2 > 0; o2 >>= 1){
            if (k < o2) red[k] += red[k + o2];
            __syncthreads();
        }
        if (k == 0){
            float c = red[0];
            if (L == 0) c += loadF(b_feat, n, isf32);
            cvec[L*FHID + n] = c;
            if (L > 0) biasv[L*FHID + n] = loadF(b_gat, (L-1)*FHID + n, isf32);
        }
    } else {
        int gt = (bid - 512)*256 + t;
        for (int i = gt; i < FHID*FHID; i += 16*256) hp[i] = loadF(wfc, i, isf32);
        if (gt < FHID*NCLS) hp[16384 + gt] = loadF(wcls, gt, isf32);
        if (gt >= 2048 && gt < 2048 + 3*FHID){
            int i = gt - 2048;
            hp[18320 + i] = loadF(attl, i, isf32);
            hp[18704 + i] = loadF(attr, i, isf32);
        }
        if (gt >= 2560 && gt < 2560 + FHID){
            int tt = gt - 2560;
            hp[17664 + tt] = loadF(bnfg, tt, isf32);
            hp[17792 + tt] = loadF(bnfb, tt, isf32);
            hp[17920 + tt] = loadF(bfc,  tt, isf32);
            hp[18048 + tt] = loadF(bnhg, tt, isf32);
            hp[18176 + tt] = loadF(bnhb, tt, isf32);
        }
        if (gt >= 3072 && gt < 3072 + NCLS) hp[18304 + (gt - 3072)] = loadF(bcls, gt - 3072, isf32);
    }
}

// ---------------- MFMA GEMM: swapped operands + fused node_alpha epilogue -----------
// 16 rows/wave: 3125 waves (~3/SIMD) for latency hiding on this small kernel.
__global__ __launch_bounds__(256) void gemm128(const void* __restrict__ A,
                                               const u16* __restrict__ Wt,
                                               const float* __restrict__ cvec,
                                               u16* __restrict__ out, int relu,
                                               int araw, const int* __restrict__ flag,
                                               const float* __restrict__ attl,
                                               const float* __restrict__ attr,
                                               float* __restrict__ al,
                                               float* __restrict__ ar)
{
    int wave = threadIdx.x >> 6;
    int lane = threadIdx.x & 63;
    int m = lane & 15, quad = lane >> 4;
    int row = blockIdx.x * 64 + wave * 16 + m;
    bool v0 = row < NN;
    bool f32in = araw && flag[0];
    const u16*  Au = (const u16*)A;
    const float* Af = (const float*)A;
    f32x4 acc[8];
#pragma unroll
    for (int j = 0; j < 8; j++) acc[j] = (f32x4){0.f,0.f,0.f,0.f};
#pragma unroll
    for (int t = 0; t < 4; t++){
        bf16x8 a0 = {0,0,0,0,0,0,0,0};
        int kof = t*32 + quad*8;
        if (f32in){
            if (v0){
                const float* p = Af + (size_t)row*FHID + kof;
                float4 u0 = *(const float4*)p, u1 = *(const float4*)(p+4);
                a0[0]=(short)f2bf(u0.x); a0[1]=(short)f2bf(u0.y);
                a0[2]=(short)f2bf(u0.z); a0[3]=(short)f2bf(u0.w);
                a0[4]=(short)f2bf(u1.x); a0[5]=(short)f2bf(u1.y);
                a0[6]=(short)f2bf(u1.z); a0[7]=(short)f2bf(u1.w);
            }
        } else {
            if (v0) a0 = *(const bf16x8*)(Au + (size_t)row*FHID + kof);
        }
#pragma unroll
        for (int ct = 0; ct < 8; ct++){
            bf16x8 wfrag = *(const bf16x8*)(Wt + (ct*16 + m)*FHID + kof);
            acc[ct] = __builtin_amdgcn_mfma_f32_16x16x32_bf16(wfrag, a0, acc[ct], 0, 0, 0);
        }
    }
    bool doa = (attl != nullptr);
    float sl[4] = {0.f,0.f,0.f,0.f};
    float sr[4] = {0.f,0.f,0.f,0.f};
#pragma unroll
    for (int ct = 0; ct < 8; ct++){
        int cb = ct*16 + quad*4;
        float4 cv = *(const float4*)(cvec + cb);
        float w0 = acc[ct][0] + cv.x;
        float w1 = acc[ct][1] + cv.y;
        float w2 = acc[ct][2] + cv.z;
        float w3 = acc[ct][3] + cv.w;
        if (relu){
            w0 = fmaxf(w0, 0.f); w1 = fmaxf(w1, 0.f);
            w2 = fmaxf(w2, 0.f); w3 = fmaxf(w3, 0.f);
        }
        if (doa){
            int h = ct >> 1;
            float4 tl = *(const float4*)(attl + cb);
            float4 tr = *(const float4*)(attr + cb);
            sl[h] += w0*tl.x + w1*tl.y + w2*tl.z + w3*tl.w;
            sr[h] += w0*tr.x + w1*tr.y + w2*tr.z + w3*tr.w;
        }
        if (v0){
            uint2 st; st.x = pack2(w0, w1); st.y = pack2(w2, w3);
            *(uint2*)(out + (size_t)row*FHID + cb) = st;
        }
    }
    if (doa){
#pragma unroll
        for (int h = 0; h < 4; h++){
            sl[h] += __shfl_xor(sl[h], 16, 64);
            sl[h] += __shfl_xor(sl[h], 32, 64);
            sr[h] += __shfl_xor(sr[h], 16, 64);
            sr[h] += __shfl_xor(sr[h], 32, 64);
        }
        if (v0){
            al[row*NHEAD + quad] = sl[quad];
            ar[row*NHEAD + quad] = sr[quad];
        }
    }
}

// ---------------- bin edges into slack buckets (no global histogram needed) ---------
__global__ __launch_bounds__(256) void bin_edges(const int* __restrict__ srcp,
        const int* __restrict__ dstp, int* __restrict__ gcur, u64* __restrict__ binned)
{
    __shared__ int h[BK], lb[BK], gb[BK], cur[BK];
    __shared__ u64 stage[BCH];
    int t = threadIdx.x;
    h[t] = 0;
    __syncthreads();
    int base = blockIdx.x * BCH;
    int sv[8], dv[8];
#pragma unroll
    for (int k = 0; k < 8; k++){
        int e = base + k*256 + t;
        int d = -1, s = 0;
        if (e < EE){
            d = dstp[e]; s = srcp[e];
            if ((u32)d >= NN) d = -1;
        }
        sv[k] = s; dv[k] = d;
        if (d >= 0) atomicAdd(&h[d >> 8], 1);
    }
    __syncthreads();
    lb[t] = h[t];
    __syncthreads();
    for (int off = 1; off < BK; off <<= 1){
        int x = (t >= off) ? lb[t - off] : 0;
        __syncthreads();
        lb[t] += x;
        __syncthreads();
    }
    int excl = lb[t] - h[t];
    int tot  = lb[BK-1];
    __syncthreads();
    lb[t] = excl;
    gb[t] = h[t] ? atomicAdd(&gcur[t], h[t]) : 0;
    cur[t] = 0;
    __syncthreads();
#pragma unroll
    for (int k = 0; k < 8; k++){
        int d = dv[k];
        if (d >= 0){
            int b = d >> 8;
            int p = lb[b] + atomicAdd(&cur[b], 1);
            stage[p] = ((u64)(u32)d << 32) | (u32)sv[k];
        }
    }
    __syncthreads();
    for (int i = t; i < tot; i += 256){
        u64 pr = stage[i];
        int b = (int)(pr >> 40);
        binned[gb[b] + (i - lb[b])] = pr;
    }
}

// ---------------- per-bucket CSR: rowdeg int2 {start,end} into slack colbuf ---------
__global__ __launch_bounds__(512) void build_csr(const u64* __restrict__ binned,
        const int* __restrict__ gcur, int2* __restrict__ rowdeg, int* __restrict__ colbuf)
{
    __shared__ int deg[BK], ls[BK], cur[BK];
    __shared__ int colstage[CAPB];
    int b = blockIdx.x, t = threadIdx.x;
    int gb = b * CAPB;
    int cnt = gcur[b] - gb;
    if (cnt < 0) cnt = 0;
    if (cnt > CAPB) cnt = CAPB;
    if (t < BK) deg[t] = 0;
    __syncthreads();
    for (int i = t; i < cnt; i += 512){
        int d = (int)(binned[gb + i] >> 32);
        atomicAdd(&deg[d & 255], 1);
    }
    __syncthreads();
    if (t < BK) ls[t] = deg[t];
    __syncthreads();
    for (int off = 1; off < BK; off <<= 1){
        int x = (t < BK && t >= off) ? ls[t - off] : 0;
        __syncthreads();
        if (t < BK) ls[t] += x;
        __syncthreads();
    }
    if (t < BK){
        int excl = ls[t] - deg[t];
        int node = b*256 + t;
        if (node < NN) rowdeg[node] = (int2){gb + excl, gb + excl + deg[t]};
        cur[t] = excl;
    }
    __syncthreads();
    for (int i = t; i < cnt; i += 512){
        u64 pr = binned[gb + i];
        int d = (int)(pr >> 32) & 255;
        int s = (int)(u32)pr;
        int p = atomicAdd(&cur[d], 1);
        colstage[p] = s;
    }
    __syncthreads();
    for (int i = t; i < cnt; i += 512) colbuf[gb + i] = colstage[i];
}

// ---------------- SuperGAT conv: ONE NODE PER WAVE, depth-3 gather pipeline -------
// 4 lane-groups process 4 edges of the SAME node per iteration (wave-uniform trip).
// Round-3/4 lesson: under __launch_bounds__(256,8) (64-VGPR cap) the scheduler
// pre-emptively demotes pipeline slots to scratch (WRITE_SIZE 12.5 -> 257/457 MB)
// while reporting VGPR=32. Fix: (a) relax to (256,6) (~80-VGPR cap; achieved
// occupancy was only 66% anyway so a 75% static cap sacrifices nothing), and
// (b) keep the round-2 PROVEN rotation CFG (incremental prologue, alternating
// names, if(it==1){comp;break;} exits), extended from 2 to 3 slots.
__device__ __forceinline__ void load_e(uint4& X, float& F, int e, int e1,
        const int* __restrict__ colbuf, const u16* __restrict__ hh,
        const float* __restrict__ al, int chbase, int head)
{
    int si = colbuf[e];                 // +64-int slack allocated past BK*CAPB
    bool bad = (e >= e1) || ((u32)si >= NN);
    if (bad) si = 0;
    X = *(const uint4*)(hh + (size_t)si*FHID + chbase);
    float f = al[si*NHEAD + head];
    F = bad ? -1e30f : f;               // masked: pe = exp(-huge) == 0 exactly
}

__device__ __forceinline__ void comp_e(uint4 X, float F,
        const float* hd, float arn, float& s, float* o)
{
    float hs[8]; unpk8(X, hs);
    float lg = hd[0]*hs[0]+hd[1]*hs[1]+hd[2]*hs[2]+hd[3]*hs[3]
             + hd[4]*hs[4]+hd[5]*hs[5]+hd[6]*hs[6]+hd[7]*hs[7];
    lg = quad_red(lg);
    float a2 = (F + arn) * (1.0f / (1.0f + __expf(-lg)));
    a2 = fmaxf(a2, 0.2f*a2);            // leaky_relu(a2, 0.2) for all signs
    float pe = __expf(fminf(a2, 60.f));
    s += pe;
#pragma unroll
    for (int i = 0; i < 8; i++) o[i] += pe*hs[i];
}

__global__ __launch_bounds__(256, 6) void supergat_conv(const u16* __restrict__ hh,
        const float* __restrict__ al, const float* __restrict__ ar,
        const int2* __restrict__ rowdeg, const int* __restrict__ colbuf,
        const float* __restrict__ bias, u16* __restrict__ hout)
{
    int node = (blockIdx.x*256 + threadIdx.x) >> 6;     // one wave per node
    int lane = threadIdx.x & 63;
    int group = lane >> 4;
    int gl    = lane & 15;
    int head  = gl >> 2;
    int chbase = head*32 + (gl & 3)*8;
    if (node >= NN) return;                              // wave-uniform

    uint4 hdv = *(const uint4*)(hh + (size_t)node*FHID + chbase);
    float hd[8]; unpk8(hdv, hd);
    float arn = ar[node*NHEAD + head];
    float aln = al[node*NHEAD + head];

    // self-loop term (identical in all groups; count it once via group-0 mask)
    float d = hd[0]*hd[0]+hd[1]*hd[1]+hd[2]*hd[2]+hd[3]*hd[3]
            + hd[4]*hd[4]+hd[5]*hd[5]+hd[6]*hd[6]+hd[7]*hd[7];
    d = quad_red(d);
    float a = (aln + arn) * (1.0f / (1.0f + __expf(-d)));
    a = fmaxf(a, 0.2f*a);
    float p = __expf(fminf(a, 60.f));
    if (group != 0) p = 0.f;
    float s = p;
    float o[8];
#pragma unroll
    for (int i = 0; i < 8; i++) o[i] = p*hd[i];

    int2 rd = rowdeg[node];
    int e0 = rd.x, e1 = rd.y;
    if (e0 < 0) e0 = 0;
    if (e1 > BK*CAPB) e1 = BK*CAPB;
    int it = (e1 - e0 + 3) >> 2;                         // wave-uniform trip count
    int e = e0 + group;

    if (it > 0){
        uint4 XA, XB, XC;
        float FA, FB, FC;
        load_e(XA, FA, e,   e1, colbuf, hh, al, chbase, head);
        load_e(XB, FB, e+4, e1, colbuf, hh, al, chbase, head);  // masked if beyond
        e += 8;
        while (true){
            if (it == 1){ comp_e(XA, FA, hd, arn, s, o); break; }
            load_e(XC, FC, e, e1, colbuf, hh, al, chbase, head); e += 4;
            comp_e(XA, FA, hd, arn, s, o);
            --it;
            if (it == 1){ comp_e(XB, FB, hd, arn, s, o); break; }
            load_e(XA, FA, e, e1, colbuf, hh, al, chbase, head); e += 4;
            comp_e(XB, FB, hd, arn, s, o);
            --it;
            if (it == 1){ comp_e(XC, FC, hd, arn, s, o); break; }
            load_e(XB, FB, e, e1, colbuf, hh, al, chbase, head); e += 4;
            comp_e(XC, FC, hd, arn, s, o);
            --it;
        }
    }

    // combine the 4 groups' partials (same channels, disjoint edge subsets)
    s += __shfl_xor(s, 16, 64);
    s += __shfl_xor(s, 32, 64);
#pragma unroll
    for (int i = 0; i < 8; i++){
        o[i] += __shfl_xor(o[i], 16, 64);
        o[i] += __shfl_xor(o[i], 32, 64);
    }

    if (group == 0){
        float inv = 1.0f / (s + 1e-16f);
        uint4 w;
        w.x = pack2(fmaxf(o[0]*inv + bias[chbase+0], 0.f),
                    fmaxf(o[1]*inv + bias[chbase+1], 0.f));
        w.y = pack2(fmaxf(o[2]*inv + bias[chbase+2], 0.f),
                    fmaxf(o[3]*inv + bias[chbase+3], 0.f));
        w.z = pack2(fmaxf(o[4]*inv + bias[chbase+4], 0.f),
                    fmaxf(o[5]*inv + bias[chbase+5], 0.f));
        w.w = pack2(fmaxf(o[6]*inv + bias[chbase+6], 0.f),
                    fmaxf(o[7]*inv + bias[chbase+7], 0.f));
        *(uint4*)(hout + (size_t)node*FHID + chbase) = w;
    }
}

// ---------------- fused pool + head: one block per graph ----------------------------
__global__ void pool_head(const u16* __restrict__ h, const int* __restrict__ batch,
                          const float* __restrict__ hp, const int* __restrict__ flag,
                          void* __restrict__ out)
{
    __shared__ int bounds[2];
    __shared__ float gb[FHID];
    __shared__ float g2[FHID];
    __shared__ float lg[16];
    int gi = blockIdx.x, t = threadIdx.x;
    int isf32 = flag[0];
    if (t < 2){
        int target = gi + t;
        int lo = 0, hi = NN;
        while (lo < hi){
            int mid = (lo + hi) >> 1;
            if (batch[mid] < target) lo = mid + 1; else hi = mid;
        }
        bounds[t] = lo;
    }
    __syncthreads();
    float s0 = 0.f, s1 = 0.f, s2 = 0.f, s3 = 0.f;
    int node = bounds[0], nend = bounds[1];
    for (; node + 3 < nend; node += 4){
        s0 += bf2f(h[(size_t)(node+0)*FHID + t]);
        s1 += bf2f(h[(size_t)(node+1)*FHID + t]);
        s2 += bf2f(h[(size_t)(node+2)*FHID + t]);
        s3 += bf2f(h[(size_t)(node+3)*FHID + t]);
    }
    for (; node < nend; node++) s0 += bf2f(h[(size_t)node*FHID + t]);
    float acc0 = (s0 + s1) + (s2 + s3);
    const float rs = rsqrtf(1.0f + 1e-5f);
    gb[t] = acc0 * (hp[17664 + t] * rs) + hp[17792 + t];
    __syncthreads();
    float acc = hp[17920 + t];
    for (int k = 0; k < FHID; k++) acc += gb[k] * hp[k*FHID + t];
    acc = fmaxf(acc, 0.f);
    g2[t] = acc * (hp[18048 + t] * rs) + hp[18176 + t];
    __syncthreads();
    if (t < NCLS){
        float l = hp[18304 + t];
        for (int k = 0; k < FHID; k++) l += g2[k] * hp[16384 + k*NCLS + t];
        lg[t] = l;
    }
    __syncthreads();
    if (t == 0){
        float mx = lg[0];
        for (int j = 1; j < NCLS; j++) mx = fmaxf(mx, lg[j]);
        float se = 0.f;
        for (int j = 0; j < NCLS; j++) se += __expf(lg[j] - mx);
        float lse = logf(se) + mx;
        if (isf32){
            float* o = (float*)out;
            for (int j = 0; j < NCLS; j++) o[gi*NCLS + j] = lg[j] - lse;
            if (gi == 0) o[NGRAPH*NCLS] = 0.f;
        } else {
            u16* o = (u16*)out;
            for (int j = 0; j < NCLS; j++) o[gi*NCLS + j] = f2bf(lg[j] - lse);
            if (gi == 0) o[NGRAPH*NCLS] = 0;
        }
    }
}

extern "C" void kernel_launch(void* const* d_in, const int* in_sizes, int n_in,
                              void* d_out, int out_size, void* d_ws, size_t ws_size,
                              hipStream_t stream)
{
    (void)in_sizes; (void)n_in; (void)out_size; (void)ws_size;
    const void* x         = d_in[0];
    const int* edge       = (const int*)d_in[1];
    const int* batch      = (const int*)d_in[2];

    char* ws = (char*)d_ws;
    size_t off = 0;
    auto alloc = [&](size_t bytes) -> char* {
        char* p = ws + off; off += (bytes + 255) & ~(size_t)255; return p;
    };
    int*   dflag   = (int*)  alloc(256);
    u16*   WtAll   = (u16*)  alloc((size_t)4*FHID*FHID*2);
    float* cvecAll = (float*)alloc((size_t)4*FHID*4);
    float* biasv   = (float*)alloc((size_t)4*FHID*4);
    float* headp   = (float*)alloc((size_t)19088*4);
    float* al      = (float*)alloc((size_t)NN*NHEAD*4);
    float* ar      = (float*)alloc((size_t)NN*NHEAD*4);
    int*   gcur    = (int*)  alloc((size_t)BK*4);
    int2*  rowdeg  = (int2*) alloc((size_t)NN*8);
    int*   colbuf  = (int*)  alloc((size_t)(BK*CAPB + 64)*4);  // +64 ints: depth-3 pipeline over-read slack
    u16*   hA      = (u16*)  alloc((size_t)NN*FHID*2);
    u16*   hB      = (u16*)  alloc((size_t)NN*FHID*2);
    // binned (256*6144*8 = 12.58 MB) aliases hB (12.8 MB): hB first written by the
    // layer-1 gemm, strictly after build_csr (stream-ordered).
    u64*   binned  = (u64*)hB;

    const int* srcp = edge;
    const int* dstp = edge + EE;

    prep_all<<<528, 256, 0, stream>>>((const u16*)x,
        d_in[5], d_in[6], d_in[3], d_in[4], d_in[9], d_in[7], d_in[8], d_in[12],
        d_in[15], d_in[16], d_in[13], d_in[14], d_in[17], d_in[18], d_in[19], d_in[20],
        d_in[10], d_in[11],
        WtAll, cvecAll, biasv, headp, dflag, gcur);

    bin_edges<<<NBLK_E, 256, 0, stream>>>(srcp, dstp, gcur, binned);
    build_csr<<<NBUCK, 512, 0, stream>>>(binned, gcur, rowdeg, colbuf);

    // feature layer: reads raw x (f32 or bf16 per flag), converts in-register
    gemm128<<<(NN + 63)/64, 256, 0, stream>>>(x, WtAll, cvecAll, hA, 1, 1, dflag,
                                              nullptr, nullptr, nullptr, nullptr);

    for (int i = 0; i < 3; i++){
        gemm128<<<(NN + 63)/64, 256, 0, stream>>>(hA, WtAll + (i+1)*FHID*FHID,
                                                  cvecAll + (i+1)*FHID, hB, 0, 0, dflag,
                                                  headp + 18320 + i*FHID,
                                                  headp + 18704 + i*FHID, al, ar);
        supergat_conv<<<(NN + 3)/4, 256, 0, stream>>>(hB, al, ar, rowdeg, colbuf,
                                                      biasv + (i+1)*FHID, hA);
    }

    pool_head<<<NGRAPH, 128, 0, stream>>>(hA, batch, headp, dflag, d_out);
}

// Round 6
// 380.839 us; speedup vs baseline: 1.9980x; 1.0512x over previous
//
#include <hip/hip_runtime.h>

#define NN 50000
#define EE 800000
#define FHID 128
#define NHEAD 4
#define NGRAPH 512
#define NCLS 10
#define BK 256            // buckets (dst>>8)
#define BCH 2048          // edges per block in bin kernel (391 blocks)
#define NBLK_E 391        // ceil(EE/BCH)
#define NBUCK 196         // ceil(NN/256)
#define CAPB 6144         // slack capacity per bucket (mean 4096, 32-sigma headroom)

typedef unsigned short u16;
typedef unsigned int u32;
typedef unsigned long long u64;
typedef __attribute__((ext_vector_type(8))) short bf16x8;
typedef __attribute__((ext_vector_type(4))) float f32x4;
typedef __attribute__((ext_vector_type(2))) float f32x2;

__device__ __forceinline__ float bf2f(u16 u){
    union { u32 i; float f; } v; v.i = ((u32)u) << 16; return v.f;
}
__device__ __forceinline__ float bflo(u32 u){
    union { u32 i; float f; } v; v.i = u << 16; return v.f;
}
__device__ __forceinline__ float bfhi(u32 u){
    union { u32 i; float f; } v; v.i = u & 0xffff0000u; return v.f;
}
__device__ __forceinline__ u16 f2bf(float f){
    union { float f; u32 i; } v; v.f = f;
    u32 r = v.i + 0x7fffu + ((v.i >> 16) & 1u);
    return (u16)(r >> 16);
}
__device__ __forceinline__ u32 pack2(float a, float b){
    return ((u32)f2bf(b) << 16) | f2bf(a);
}
__device__ __forceinline__ float loadF(const void* p, int i, int isf32){
    return isf32 ? ((const float*)p)[i] : bf2f(((const u16*)p)[i]);
}
__device__ __forceinline__ void unpk8(uint4 v, float* f){
    f[0]=bflo(v.x); f[1]=bfhi(v.x);
    f[2]=bflo(v.y); f[3]=bfhi(v.y);
    f[4]=bflo(v.z); f[5]=bfhi(v.z);
    f[6]=bflo(v.w); f[7]=bfhi(v.w);
}
// packed-pair unpack: h[j] = {lo, hi} of word j — feeds f32x2 (v_pk_fma_f32) math
__device__ __forceinline__ void unpk8v(uint4 v, f32x2* h){
    h[0] = (f32x2){bflo(v.x), bfhi(v.x)};
    h[1] = (f32x2){bflo(v.y), bfhi(v.y)};
    h[2] = (f32x2){bflo(v.z), bfhi(v.z)};
    h[3] = (f32x2){bflo(v.w), bfhi(v.w)};
}

// 4-lane (quad) butterfly reduce in the VALU pipe via DPP quad_perm.
// Quads are always exec-uniform here (4 lanes of a quad share a head of one node).
__device__ __forceinline__ float quad_red(float x){
    int t0 = __builtin_amdgcn_mov_dpp(__float_as_int(x), 0xB1, 0xF, 0xF, true); // [1,0,3,2]
    float y = x + __int_as_float(t0);
    int t1 = __builtin_amdgcn_mov_dpp(__float_as_int(y), 0x4E, 0xF, 0xF, true); // [2,3,0,1]
    return y + __int_as_float(t1);
}

// block-local dtype detect: count bf16-plausible halfwords in x[0..1023] (lds reduce)
__device__ int detect_local(const u16* x, int tid, int nthreads, int* lds){
    int ok = 0;
    for (int i = tid; i < 1024; i += nthreads){
        u16 u = x[i];
        int e = (u >> 7) & 0xFF;
        if ((u & 0x7fff) == 0 || (e >= 0x70 && e <= 0x85)) ok++;
    }
    lds[tid] = ok;
    __syncthreads();
    for (int o2 = nthreads >> 1; o2 > 0; o2 >>= 1){
        if (tid < o2) lds[tid] += lds[tid + o2];
        __syncthreads();
    }
    int r = (lds[0] < 900) ? 1 : 0;   // 1 = f32 inputs
    __syncthreads();
    return r;
}

// ---------------- fused prep: weights (blocks 0..511) + head/att (512..527) ---------
// block 0 also initializes gcur[t] = t*CAPB (slack-bucket bases)
__global__ __launch_bounds__(256) void prep_all(
        const u16* __restrict__ xz,
        const void* w_feat, const void* b_feat, const void* bn_feat_g, const void* bn_feat_b,
        const void* w_gat, const void* bn_conv_g, const void* bn_conv_b, const void* b_gat,
        const void* wfc, const void* bfc, const void* bnfg, const void* bnfb,
        const void* bnhg, const void* bnhb, const void* wcls, const void* bcls,
        const void* attl, const void* attr,
        u16* __restrict__ Wt, float* __restrict__ cvec, float* __restrict__ biasv,
        float* __restrict__ hp, int* __restrict__ dflag, int* __restrict__ gcur)
{
    __shared__ int ldsi[256];
    __shared__ float red[128];
    int bid = blockIdx.x, t = threadIdx.x;
    int isf32 = detect_local(xz, t, 256, ldsi);
    if (bid == 0){
        if (t == 0) dflag[0] = isf32;
        gcur[t] = t * CAPB;
    }

    if (bid < 512){
        if (t >= 128) return;
        int L = bid >> 7;
        int n = bid & 127;
        int k = t;
        const float rs = rsqrtf(1.0f + 1e-5f);
        float wv, bg, bb;
        if (L == 0){
            wv = loadF(w_feat, k*FHID + n, isf32);
            bg = loadF(bn_feat_g, k, isf32);
            bb = loadF(bn_feat_b, k, isf32);
        } else {
            wv = loadF(w_gat, (L-1)*FHID*FHID + k*FHID + n, isf32);
            bg = loadF(bn_conv_g, (L-1)*FHID + k, isf32);
            bb = loadF(bn_conv_b, (L-1)*FHID + k, isf32);
        }
        Wt[L*FHID*FHID + n*FHID + k] = f2bf(bg * rs * wv);
        red[k] = bb * wv;
        __syncthreads();
        for (int o2 = 64; o2 > 0; o2 >>= 1){
            if (k < o2) red[k] += red[k + o2];
            __syncthreads();
        }
        if (k == 0){
            float c = red[0];
            if (L == 0) c += loadF(b_feat, n, isf32);
            cvec[L*FHID + n] = c;
            if (L > 0) biasv[L*FHID + n] = loadF(b_gat, (L-1)*FHID + n, isf32);
        }
    } else {
        int gt = (bid - 512)*256 + t;
        for (int i = gt; i < FHID*FHID; i += 16*256) hp[i] = loadF(wfc, i, isf32);
        if (gt < FHID*NCLS) hp[16384 + gt] = loadF(wcls, gt, isf32);
        if (gt >= 2048 && gt < 2048 + 3*FHID){
            int i = gt - 2048;
            hp[18320 + i] = loadF(attl, i, isf32);
            hp[18704 + i] = loadF(attr, i, isf32);
        }
        if (gt >= 2560 && gt < 2560 + FHID){
            int tt = gt - 2560;
            hp[17664 + tt] = loadF(bnfg, tt, isf32);
            hp[17792 + tt] = loadF(bnfb, tt, isf32);
            hp[17920 + tt] = loadF(bfc,  tt, isf32);
            hp[18048 + tt] = loadF(bnhg, tt, isf32);
            hp[18176 + tt] = loadF(bnhb, tt, isf32);
        }
        if (gt >= 3072 && gt < 3072 + NCLS) hp[18304 + (gt - 3072)] = loadF(bcls, gt - 3072, isf32);
    }
}

// ---------------- MFMA GEMM: swapped operands + fused node_alpha epilogue -----------
// 16 rows/wave: 3125 waves (~3/SIMD) for latency hiding on this small kernel.
__global__ __launch_bounds__(256) void gemm128(const void* __restrict__ A,
                                               const u16* __restrict__ Wt,
                                               const float* __restrict__ cvec,
                                               u16* __restrict__ out, int relu,
                                               int araw, const int* __restrict__ flag,
                                               const float* __restrict__ attl,
                                               const float* __restrict__ attr,
                                               float* __restrict__ al,
                                               float* __restrict__ ar)
{
    int wave = threadIdx.x >> 6;
    int lane = threadIdx.x & 63;
    int m = lane & 15, quad = lane >> 4;
    int row = blockIdx.x * 64 + wave * 16 + m;
    bool v0 = row < NN;
    bool f32in = araw && flag[0];
    const u16*  Au = (const u16*)A;
    const float* Af = (const float*)A;
    f32x4 acc[8];
#pragma unroll
    for (int j = 0; j < 8; j++) acc[j] = (f32x4){0.f,0.f,0.f,0.f};
#pragma unroll
    for (int t = 0; t < 4; t++){
        bf16x8 a0 = {0,0,0,0,0,0,0,0};
        int kof = t*32 + quad*8;
        if (f32in){
            if (v0){
                const float* p = Af + (size_t)row*FHID + kof;
                float4 u0 = *(const float4*)p, u1 = *(const float4*)(p+4);
                a0[0]=(short)f2bf(u0.x); a0[1]=(short)f2bf(u0.y);
                a0[2]=(short)f2bf(u0.z); a0[3]=(short)f2bf(u0.w);
                a0[4]=(short)f2bf(u1.x); a0[5]=(short)f2bf(u1.y);
                a0[6]=(short)f2bf(u1.z); a0[7]=(short)f2bf(u1.w);
            }
        } else {
            if (v0) a0 = *(const bf16x8*)(Au + (size_t)row*FHID + kof);
        }
#pragma unroll
        for (int ct = 0; ct < 8; ct++){
            bf16x8 wfrag = *(const bf16x8*)(Wt + (ct*16 + m)*FHID + kof);
            acc[ct] = __builtin_amdgcn_mfma_f32_16x16x32_bf16(wfrag, a0, acc[ct], 0, 0, 0);
        }
    }
    bool doa = (attl != nullptr);
    float sl[4] = {0.f,0.f,0.f,0.f};
    float sr[4] = {0.f,0.f,0.f,0.f};
#pragma unroll
    for (int ct = 0; ct < 8; ct++){
        int cb = ct*16 + quad*4;
        float4 cv = *(const float4*)(cvec + cb);
        float w0 = acc[ct][0] + cv.x;
        float w1 = acc[ct][1] + cv.y;
        float w2 = acc[ct][2] + cv.z;
        float w3 = acc[ct][3] + cv.w;
        if (relu){
            w0 = fmaxf(w0, 0.f); w1 = fmaxf(w1, 0.f);
            w2 = fmaxf(w2, 0.f); w3 = fmaxf(w3, 0.f);
        }
        if (doa){
            int h = ct >> 1;
            float4 tl = *(const float4*)(attl + cb);
            float4 tr = *(const float4*)(attr + cb);
            sl[h] += w0*tl.x + w1*tl.y + w2*tl.z + w3*tl.w;
            sr[h] += w0*tr.x + w1*tr.y + w2*tr.z + w3*tr.w;
        }
        if (v0){
            uint2 st; st.x = pack2(w0, w1); st.y = pack2(w2, w3);
            *(uint2*)(out + (size_t)row*FHID + cb) = st;
        }
    }
    if (doa){
#pragma unroll
        for (int h = 0; h < 4; h++){
            sl[h] += __shfl_xor(sl[h], 16, 64);
            sl[h] += __shfl_xor(sl[h], 32, 64);
            sr[h] += __shfl_xor(sr[h], 16, 64);
            sr[h] += __shfl_xor(sr[h], 32, 64);
        }
        if (v0){
            al[row*NHEAD + quad] = sl[quad];
            ar[row*NHEAD + quad] = sr[quad];
        }
    }
}

// ---------------- bin edges into slack buckets (no global histogram needed) ---------
__global__ __launch_bounds__(256) void bin_edges(const int* __restrict__ srcp,
        const int* __restrict__ dstp, int* __restrict__ gcur, u64* __restrict__ binned)
{
    __shared__ int h[BK], lb[BK], gb[BK], cur[BK];
    __shared__ u64 stage[BCH];
    int t = threadIdx.x;
    h[t] = 0;
    __syncthreads();
    int base = blockIdx.x * BCH;
    int sv[8], dv[8];
#pragma unroll
    for (int k = 0; k < 8; k++){
        int e = base + k*256 + t;
        int d = -1, s = 0;
        if (e < EE){
            d = dstp[e]; s = srcp[e];
            if ((u32)d >= NN) d = -1;
        }
        sv[k] = s; dv[k] = d;
        if (d >= 0) atomicAdd(&h[d >> 8], 1);
    }
    __syncthreads();
    lb[t] = h[t];
    __syncthreads();
    for (int off = 1; off < BK; off <<= 1){
        int x = (t >= off) ? lb[t - off] : 0;
        __syncthreads();
        lb[t] += x;
        __syncthreads();
    }
    int excl = lb[t] - h[t];
    int tot  = lb[BK-1];
    __syncthreads();
    lb[t] = excl;
    gb[t] = h[t] ? atomicAdd(&gcur[t], h[t]) : 0;
    cur[t] = 0;
    __syncthreads();
#pragma unroll
    for (int k = 0; k < 8; k++){
        int d = dv[k];
        if (d >= 0){
            int b = d >> 8;
            int p = lb[b] + atomicAdd(&cur[b], 1);
            stage[p] = ((u64)(u32)d << 32) | (u32)sv[k];
        }
    }
    __syncthreads();
    for (int i = t; i < tot; i += 256){
        u64 pr = stage[i];
        int b = (int)(pr >> 40);
        binned[gb[b] + (i - lb[b])] = pr;
    }
}

// ---------------- per-bucket CSR: rowdeg int2 {start,end} into slack colbuf ---------
__global__ __launch_bounds__(512) void build_csr(const u64* __restrict__ binned,
        const int* __restrict__ gcur, int2* __restrict__ rowdeg, int* __restrict__ colbuf)
{
    __shared__ int deg[BK], ls[BK], cur[BK];
    __shared__ int colstage[CAPB];
    int b = blockIdx.x, t = threadIdx.x;
    int gb = b * CAPB;
    int cnt = gcur[b] - gb;
    if (cnt < 0) cnt = 0;
    if (cnt > CAPB) cnt = CAPB;
    if (t < BK) deg[t] = 0;
    __syncthreads();
    for (int i = t; i < cnt; i += 512){
        int d = (int)(binned[gb + i] >> 32);
        atomicAdd(&deg[d & 255], 1);
    }
    __syncthreads();
    if (t < BK) ls[t] = deg[t];
    __syncthreads();
    for (int off = 1; off < BK; off <<= 1){
        int x = (t < BK && t >= off) ? ls[t - off] : 0;
        __syncthreads();
        if (t < BK) ls[t] += x;
        __syncthreads();
    }
    if (t < BK){
        int excl = ls[t] - deg[t];
        int node = b*256 + t;
        if (node < NN) rowdeg[node] = (int2){gb + excl, gb + excl + deg[t]};
        cur[t] = excl;
    }
    __syncthreads();
    for (int i = t; i < cnt; i += 512){
        u64 pr = binned[gb + i];
        int d = (int)(pr >> 32) & 255;
        int s = (int)(u32)pr;
        int p = atomicAdd(&cur[d], 1);
        colstage[p] = s;
    }
    __syncthreads();
    for (int i = t; i < cnt; i += 512) colbuf[gb + i] = colstage[i];
}

// ---------------- SuperGAT conv: ONE NODE PER WAVE, round-2 proven structure ------
// Depth-2 A/B rotation @ __launch_bounds__(256,8): the only shape that has
// compiled clean (VGPR 32-40, no scratch) across 5 rounds. New in v6: all
// 8-channel dot/accumulate math in f32x2 ext-vectors so the backend can select
// full-rate v_pk_fma_f32 (gfx90a+/gfx950 packed FP32) — per-edge VALU ~48->~36
// per 4-edge iteration. Worst case (no pk selection) identical scalar code.
__device__ __forceinline__ void load_e(uint4& X, float& F, int e, int e1,
        const int* __restrict__ colbuf, const u16* __restrict__ hh,
        const float* __restrict__ al, int chbase, int head)
{
    int si = colbuf[e];                 // +64-int slack allocated past BK*CAPB
    bool bad = (e >= e1) || ((u32)si >= NN);
    if (bad) si = 0;
    X = *(const uint4*)(hh + (size_t)si*FHID + chbase);
    float f = al[si*NHEAD + head];
    F = bad ? -1e30f : f;               // masked: pe = exp(-huge) == 0 exactly
}

__device__ __forceinline__ void comp_e(uint4 X, float F,
        const f32x2* hd2, float arn, float& s, f32x2* o2)
{
    f32x2 hs2[4]; unpk8v(X, hs2);
    f32x2 d2 = hd2[0]*hs2[0];
    d2 = hd2[1]*hs2[1] + d2;
    d2 = hd2[2]*hs2[2] + d2;
    d2 = hd2[3]*hs2[3] + d2;
    float lg = quad_red(d2[0] + d2[1]);
    float a2 = (F + arn) * (1.0f / (1.0f + __expf(-lg)));
    a2 = fmaxf(a2, 0.2f*a2);            // leaky_relu(a2, 0.2) for all signs
    float pe = __expf(fminf(a2, 60.f));
    s += pe;
    f32x2 pe2 = (f32x2){pe, pe};
    o2[0] = pe2*hs2[0] + o2[0];
    o2[1] = pe2*hs2[1] + o2[1];
    o2[2] = pe2*hs2[2] + o2[2];
    o2[3] = pe2*hs2[3] + o2[3];
}

__global__ __launch_bounds__(256, 8) void supergat_conv(const u16* __restrict__ hh,
        const float* __restrict__ al, const float* __restrict__ ar,
        const int2* __restrict__ rowdeg, const int* __restrict__ colbuf,
        const float* __restrict__ bias, u16* __restrict__ hout)
{
    int node = (blockIdx.x*256 + threadIdx.x) >> 6;     // one wave per node
    int lane = threadIdx.x & 63;
    int group = lane >> 4;
    int gl    = lane & 15;
    int head  = gl >> 2;
    int chbase = head*32 + (gl & 3)*8;
    if (node >= NN) return;                              // wave-uniform

    uint4 hdv = *(const uint4*)(hh + (size_t)node*FHID + chbase);
    f32x2 hd2[4]; unpk8v(hdv, hd2);
    float arn = ar[node*NHEAD + head];
    float aln = al[node*NHEAD + head];

    // self-loop term (identical in all groups; count it once via group-0 mask)
    f32x2 dd2 = hd2[0]*hd2[0];
    dd2 = hd2[1]*hd2[1] + dd2;
    dd2 = hd2[2]*hd2[2] + dd2;
    dd2 = hd2[3]*hd2[3] + dd2;
    float d = quad_red(dd2[0] + dd2[1]);
    float a = (aln + arn) * (1.0f / (1.0f + __expf(-d)));
    a = fmaxf(a, 0.2f*a);
    float p = __expf(fminf(a, 60.f));
    if (group != 0) p = 0.f;
    float s = p;
    f32x2 p2 = (f32x2){p, p};
    f32x2 o2[4];
    o2[0] = p2*hd2[0];
    o2[1] = p2*hd2[1];
    o2[2] = p2*hd2[2];
    o2[3] = p2*hd2[3];

    int2 rd = rowdeg[node];
    int e0 = rd.x, e1 = rd.y;
    if (e0 < 0) e0 = 0;
    if (e1 > BK*CAPB) e1 = BK*CAPB;
    int it = (e1 - e0 + 3) >> 2;                         // wave-uniform trip count
    int e = e0 + group;

    if (it > 0){
        uint4 xA, xB; float fA, fB;
        load_e(xA, fA, e, e1, colbuf, hh, al, chbase, head);
        e += 4;
        while (true){
            if (it == 1){ comp_e(xA, fA, hd2, arn, s, o2); break; }
            load_e(xB, fB, e, e1, colbuf, hh, al, chbase, head); e += 4;
            comp_e(xA, fA, hd2, arn, s, o2);
            --it;
            if (it == 1){ comp_e(xB, fB, hd2, arn, s, o2); break; }
            load_e(xA, fA, e, e1, colbuf, hh, al, chbase, head); e += 4;
            comp_e(xB, fB, hd2, arn, s, o2);
            --it;
        }
    }

    // combine the 4 groups' partials (same channels, disjoint edge subsets)
    s += __shfl_xor(s, 16, 64);
    s += __shfl_xor(s, 32, 64);
#pragma unroll
    for (int i = 0; i < 4; i++){
        float x0 = o2[i][0], x1 = o2[i][1];
        x0 += __shfl_xor(x0, 16, 64);
        x0 += __shfl_xor(x0, 32, 64);
        x1 += __shfl_xor(x1, 16, 64);
        x1 += __shfl_xor(x1, 32, 64);
        o2[i] = (f32x2){x0, x1};
    }

    if (group == 0){
        float inv = 1.0f / (s + 1e-16f);
        uint4 w;
        w.x = pack2(fmaxf(o2[0][0]*inv + bias[chbase+0], 0.f),
                    fmaxf(o2[0][1]*inv + bias[chbase+1], 0.f));
        w.y = pack2(fmaxf(o2[1][0]*inv + bias[chbase+2], 0.f),
                    fmaxf(o2[1][1]*inv + bias[chbase+3], 0.f));
        w.z = pack2(fmaxf(o2[2][0]*inv + bias[chbase+4], 0.f),
                    fmaxf(o2[2][1]*inv + bias[chbase+5], 0.f));
        w.w = pack2(fmaxf(o2[3][0]*inv + bias[chbase+6], 0.f),
                    fmaxf(o2[3][1]*inv + bias[chbase+7], 0.f));
        *(uint4*)(hout + (size_t)node*FHID + chbase) = w;
    }
}

// ---------------- fused pool + head: one block per graph ----------------------------
__global__ void pool_head(const u16* __restrict__ h, const int* __restrict__ batch,
                          const float* __restrict__ hp, const int* __restrict__ flag,
                          void* __restrict__ out)
{
    __shared__ int bounds[2];
    __shared__ float gb[FHID];
    __shared__ float g2[FHID];
    __shared__ float lg[16];
    int gi = blockIdx.x, t = threadIdx.x;
    int isf32 = flag[0];
    if (t < 2){
        int target = gi + t;
        int lo = 0, hi = NN;
        while (lo < hi){
            int mid = (lo + hi) >> 1;
            if (batch[mid] < target) lo = mid + 1; else hi = mid;
        }
        bounds[t] = lo;
    }
    __syncthreads();
    float s0 = 0.f, s1 = 0.f, s2 = 0.f, s3 = 0.f;
    int node = bounds[0], nend = bounds[1];
    for (; node + 3 < nend; node += 4){
        s0 += bf2f(h[(size_t)(node+0)*FHID + t]);
        s1 += bf2f(h[(size_t)(node+1)*FHID + t]);
        s2 += bf2f(h[(size_t)(node+2)*FHID + t]);
        s3 += bf2f(h[(size_t)(node+3)*FHID + t]);
    }
    for (; node < nend; node++) s0 += bf2f(h[(size_t)node*FHID + t]);
    float acc0 = (s0 + s1) + (s2 + s3);
    const float rs = rsqrtf(1.0f + 1e-5f);
    gb[t] = acc0 * (hp[17664 + t] * rs) + hp[17792 + t];
    __syncthreads();
    float acc = hp[17920 + t];
    for (int k = 0; k < FHID; k++) acc += gb[k] * hp[k*FHID + t];
    acc = fmaxf(acc, 0.f);
    g2[t] = acc * (hp[18048 + t] * rs) + hp[18176 + t];
    __syncthreads();
    if (t < NCLS){
        float l = hp[18304 + t];
        for (int k = 0; k < FHID; k++) l += g2[k] * hp[16384 + k*NCLS + t];
        lg[t] = l;
    }
    __syncthreads();
    if (t == 0){
        float mx = lg[0];
        for (int j = 1; j < NCLS; j++) mx = fmaxf(mx, lg[j]);
        float se = 0.f;
        for (int j = 0; j < NCLS; j++) se += __expf(lg[j] - mx);
        float lse = logf(se) + mx;
        if (isf32){
            float* o = (float*)out;
            for (int j = 0; j < NCLS; j++) o[gi*NCLS + j] = lg[j] - lse;
            if (gi == 0) o[NGRAPH*NCLS] = 0.f;
        } else {
            u16* o = (u16*)out;
            for (int j = 0; j < NCLS; j++) o[gi*NCLS + j] = f2bf(lg[j] - lse);
            if (gi == 0) o[NGRAPH*NCLS] = 0;
        }
    }
}

extern "C" void kernel_launch(void* const* d_in, const int* in_sizes, int n_in,
                              void* d_out, int out_size, void* d_ws, size_t ws_size,
                              hipStream_t stream)
{
    (void)in_sizes; (void)n_in; (void)out_size; (void)ws_size;
    const void* x         = d_in[0];
    const int* edge       = (const int*)d_in[1];
    const int* batch      = (const int*)d_in[2];

    char* ws = (char*)d_ws;
    size_t off = 0;
    auto alloc = [&](size_t bytes) -> char* {
        char* p = ws + off; off += (bytes + 255) & ~(size_t)255; return p;
    };
    int*   dflag   = (int*)  alloc(256);
    u16*   WtAll   = (u16*)  alloc((size_t)4*FHID*FHID*2);
    float* cvecAll = (float*)alloc((size_t)4*FHID*4);
    float* biasv   = (float*)alloc((size_t)4*FHID*4);
    float* headp   = (float*)alloc((size_t)19088*4);
    float* al      = (float*)alloc((size_t)NN*NHEAD*4);
    float* ar      = (float*)alloc((size_t)NN*NHEAD*4);
    int*   gcur    = (int*)  alloc((size_t)BK*4);
    int2*  rowdeg  = (int2*) alloc((size_t)NN*8);
    int*   colbuf  = (int*)  alloc((size_t)(BK*CAPB + 64)*4);  // +64 ints: pipeline over-read slack
    u16*   hA      = (u16*)  alloc((size_t)NN*FHID*2);
    u16*   hB      = (u16*)  alloc((size_t)NN*FHID*2);
    // binned (256*6144*8 = 12.58 MB) aliases hB (12.8 MB): hB first written by the
    // layer-1 gemm, strictly after build_csr (stream-ordered).
    u64*   binned  = (u64*)hB;

    const int* srcp = edge;
    const int* dstp = edge + EE;

    prep_all<<<528, 256, 0, stream>>>((const u16*)x,
        d_in[5], d_in[6], d_in[3], d_in[4], d_in[9], d_in[7], d_in[8], d_in[12],
        d_in[15], d_in[16], d_in[13], d_in[14], d_in[17], d_in[18], d_in[19], d_in[20],
        d_in[10], d_in[11],
        WtAll, cvecAll, biasv, headp, dflag, gcur);

    bin_edges<<<NBLK_E, 256, 0, stream>>>(srcp, dstp, gcur, binned);
    build_csr<<<NBUCK, 512, 0, stream>>>(binned, gcur, rowdeg, colbuf);

    // feature layer: reads raw x (f32 or bf16 per flag), converts in-register
    gemm128<<<(NN + 63)/64, 256, 0, stream>>>(x, WtAll, cvecAll, hA, 1, 1, dflag,
                                              nullptr, nullptr, nullptr, nullptr);

    for (int i = 0; i < 3; i++){
        gemm128<<<(NN + 63)/64, 256, 0, stream>>>(hA, WtAll + (i+1)*FHID*FHID,
                                                  cvecAll + (i+1)*FHID, hB, 0, 0, dflag,
                                                  headp + 18320 + i*FHID,
                                                  headp + 18704 + i*FHID, al, ar);
        supergat_conv<<<(NN + 3)/4, 256, 0, stream>>>(hB, al, ar, rowdeg, colbuf,
                                                      biasv + (i+1)*FHID, hA);
    }

    pool_head<<<NGRAPH, 128, 0, stream>>>(hA, batch, headp, dflag, d_out);
}

// Round 7
// 364.270 us; speedup vs baseline: 2.0889x; 1.0455x over previous
//
#include <hip/hip_runtime.h>

#define NN 50000
#define EE 800000
#define FHID 128
#define NHEAD 4
#define NGRAPH 512
#define NCLS 10
#define BK 256            // buckets (dst>>8)
#define BCH 2048          // edges per block in bin kernel (391 blocks)
#define NBLK_E 391        // ceil(EE/BCH)
#define NBUCK 196         // ceil(NN/256)
#define CAPB 6144         // slack capacity per bucket (mean 4096, 32-sigma headroom)
#define NBLK_G 782        // ceil(NN/64) gemm blocks

typedef unsigned short u16;
typedef unsigned int u32;
typedef unsigned long long u64;
typedef __attribute__((ext_vector_type(8))) short bf16x8;
typedef __attribute__((ext_vector_type(4))) float f32x4;
typedef __attribute__((ext_vector_type(2))) float f32x2;

__device__ __forceinline__ float bf2f(u16 u){
    union { u32 i; float f; } v; v.i = ((u32)u) << 16; return v.f;
}
__device__ __forceinline__ float bflo(u32 u){
    union { u32 i; float f; } v; v.i = u << 16; return v.f;
}
__device__ __forceinline__ float bfhi(u32 u){
    union { u32 i; float f; } v; v.i = u & 0xffff0000u; return v.f;
}
__device__ __forceinline__ u16 f2bf(float f){
    union { float f; u32 i; } v; v.f = f;
    u32 r = v.i + 0x7fffu + ((v.i >> 16) & 1u);
    return (u16)(r >> 16);
}
__device__ __forceinline__ u32 pack2(float a, float b){
    return ((u32)f2bf(b) << 16) | f2bf(a);
}
__device__ __forceinline__ float loadF(const void* p, int i, int isf32){
    return isf32 ? ((const float*)p)[i] : bf2f(((const u16*)p)[i]);
}
// packed-pair unpack: h[j] = {lo, hi} of word j — feeds f32x2 (v_pk_fma_f32) math
__device__ __forceinline__ void unpk8v(uint4 v, f32x2* h){
    h[0] = (f32x2){bflo(v.x), bfhi(v.x)};
    h[1] = (f32x2){bflo(v.y), bfhi(v.y)};
    h[2] = (f32x2){bflo(v.z), bfhi(v.z)};
    h[3] = (f32x2){bflo(v.w), bfhi(v.w)};
}

// 4-lane (quad) butterfly reduce in the VALU pipe via DPP quad_perm.
__device__ __forceinline__ float quad_red(float x){
    int t0 = __builtin_amdgcn_mov_dpp(__float_as_int(x), 0xB1, 0xF, 0xF, true); // [1,0,3,2]
    float y = x + __int_as_float(t0);
    int t1 = __builtin_amdgcn_mov_dpp(__float_as_int(y), 0x4E, 0xF, 0xF, true); // [2,3,0,1]
    return y + __int_as_float(t1);
}

// block-local dtype detect: count bf16-plausible halfwords in x[0..1023] (lds reduce)
__device__ int detect_local(const u16* x, int tid, int nthreads, int* lds){
    int ok = 0;
    for (int i = tid; i < 1024; i += nthreads){
        u16 u = x[i];
        int e = (u >> 7) & 0xFF;
        if ((u & 0x7fff) == 0 || (e >= 0x70 && e <= 0x85)) ok++;
    }
    lds[tid] = ok;
    __syncthreads();
    for (int o2 = nthreads >> 1; o2 > 0; o2 >>= 1){
        if (tid < o2) lds[tid] += lds[tid + o2];
        __syncthreads();
    }
    int r = (lds[0] < 900) ? 1 : 0;   // 1 = f32 inputs
    __syncthreads();
    return r;
}

// ---------------- prep body: weights (blocks 0..511) + head/att (512..527) ---------
__device__ __forceinline__ void prep_body(int bid, int t,
        const u16* __restrict__ xz,
        const void* w_feat, const void* b_feat, const void* bn_feat_g, const void* bn_feat_b,
        const void* w_gat, const void* bn_conv_g, const void* bn_conv_b, const void* b_gat,
        const void* wfc, const void* bfc, const void* bnfg, const void* bnfb,
        const void* bnhg, const void* bnhb, const void* wcls, const void* bcls,
        const void* attl, const void* attr,
        u16* __restrict__ Wt, float* __restrict__ cvec, float* __restrict__ biasv,
        float* __restrict__ hp, int* __restrict__ dflag)
{
    __shared__ int ldsi[256];
    __shared__ float red[128];
    int isf32 = detect_local(xz, t, 256, ldsi);
    if (bid == 0 && t == 0) dflag[0] = isf32;

    if (bid < 512){
        if (t >= 128) return;
        int L = bid >> 7;
        int n = bid & 127;
        int k = t;
        const float rs = rsqrtf(1.0f + 1e-5f);
        float wv, bg, bb;
        if (L == 0){
            wv = loadF(w_feat, k*FHID + n, isf32);
            bg = loadF(bn_feat_g, k, isf32);
            bb = loadF(bn_feat_b, k, isf32);
        } else {
            wv = loadF(w_gat, (L-1)*FHID*FHID + k*FHID + n, isf32);
            bg = loadF(bn_conv_g, (L-1)*FHID + k, isf32);
            bb = loadF(bn_conv_b, (L-1)*FHID + k, isf32);
        }
        Wt[L*FHID*FHID + n*FHID + k] = f2bf(bg * rs * wv);
        red[k] = bb * wv;
        __syncthreads();
        for (int o2 = 64; o2 > 0; o2 >>= 1){
            if (k < o2) red[k] += red[k + o2];
            __syncthreads();
        }
        if (k == 0){
            float c = red[0];
            if (L == 0) c += loadF(b_feat, n, isf32);
            cvec[L*FHID + n] = c;
            if (L > 0) biasv[L*FHID + n] = loadF(b_gat, (L-1)*FHID + n, isf32);
        }
    } else {
        int gt = (bid - 512)*256 + t;
        for (int i = gt; i < FHID*FHID; i += 16*256) hp[i] = loadF(wfc, i, isf32);
        if (gt < FHID*NCLS) hp[16384 + gt] = loadF(wcls, gt, isf32);
        if (gt >= 2048 && gt < 2048 + 3*FHID){
            int i = gt - 2048;
            hp[18320 + i] = loadF(attl, i, isf32);
            hp[18704 + i] = loadF(attr, i, isf32);
        }
        if (gt >= 2560 && gt < 2560 + FHID){
            int tt = gt - 2560;
            hp[17664 + tt] = loadF(bnfg, tt, isf32);
            hp[17792 + tt] = loadF(bnfb, tt, isf32);
            hp[17920 + tt] = loadF(bfc,  tt, isf32);
            hp[18048 + tt] = loadF(bnhg, tt, isf32);
            hp[18176 + tt] = loadF(bnhb, tt, isf32);
        }
        if (gt >= 3072 && gt < 3072 + NCLS) hp[18304 + (gt - 3072)] = loadF(bcls, gt - 3072, isf32);
    }
}

// ---------------- bin body: gcur is a ZERO-INITIALIZED per-bucket counter ----------
// (base t*CAPB folded into addressing; memset node provides the zero-init)
__device__ __forceinline__ void bin_body(int bid, int t,
        const int* __restrict__ srcp, const int* __restrict__ dstp,
        int* __restrict__ gcur, u64* __restrict__ binned)
{
    __shared__ int h[BK], lb[BK], gbs[BK], cur[BK];
    __shared__ u64 stage[BCH];
    h[t] = 0;
    __syncthreads();
    int base = bid * BCH;
    int sv[8], dv[8];
#pragma unroll
    for (int k = 0; k < 8; k++){
        int e = base + k*256 + t;
        int d = -1, s = 0;
        if (e < EE){
            d = dstp[e]; s = srcp[e];
            if ((u32)d >= NN) d = -1;
        }
        sv[k] = s; dv[k] = d;
        if (d >= 0) atomicAdd(&h[d >> 8], 1);
    }
    __syncthreads();
    lb[t] = h[t];
    __syncthreads();
    for (int off = 1; off < BK; off <<= 1){
        int x = (t >= off) ? lb[t - off] : 0;
        __syncthreads();
        lb[t] += x;
        __syncthreads();
    }
    int excl = lb[t] - h[t];
    int tot  = lb[BK-1];
    __syncthreads();
    lb[t] = excl;
    gbs[t] = t*CAPB + (h[t] ? atomicAdd(&gcur[t], h[t]) : 0);
    cur[t] = 0;
    __syncthreads();
#pragma unroll
    for (int k = 0; k < 8; k++){
        int d = dv[k];
        if (d >= 0){
            int b = d >> 8;
            int p = lb[b] + atomicAdd(&cur[b], 1);
            stage[p] = ((u64)(u32)d << 32) | (u32)sv[k];
        }
    }
    __syncthreads();
    for (int i = t; i < tot; i += 256){
        u64 pr = stage[i];
        int b = (int)(pr >> 40);
        binned[gbs[b] + (i - lb[b])] = pr;
    }
}

// ---------------- fused prep(0..527) + bin(528..918) -------------------------------
__global__ __launch_bounds__(256) void prep_bin(
        const u16* __restrict__ xz,
        const void* w_feat, const void* b_feat, const void* bn_feat_g, const void* bn_feat_b,
        const void* w_gat, const void* bn_conv_g, const void* bn_conv_b, const void* b_gat,
        const void* wfc, const void* bfc, const void* bnfg, const void* bnfb,
        const void* bnhg, const void* bnhb, const void* wcls, const void* bcls,
        const void* attl, const void* attr,
        u16* __restrict__ Wt, float* __restrict__ cvec, float* __restrict__ biasv,
        float* __restrict__ hp, int* __restrict__ dflag,
        const int* __restrict__ srcp, const int* __restrict__ dstp,
        int* __restrict__ gcur, u64* __restrict__ binned)
{
    if (blockIdx.x < 528){
        prep_body(blockIdx.x, threadIdx.x, xz, w_feat, b_feat, bn_feat_g, bn_feat_b,
                  w_gat, bn_conv_g, bn_conv_b, b_gat, wfc, bfc, bnfg, bnfb,
                  bnhg, bnhb, wcls, bcls, attl, attr, Wt, cvec, biasv, hp, dflag);
    } else {
        bin_body(blockIdx.x - 528, threadIdx.x, srcp, dstp, gcur, binned);
    }
}

// ---------------- MFMA GEMM body: swapped operands + fused node_alpha epilogue ------
__device__ __forceinline__ void gemm_body(int bid, int tid,
        const void* __restrict__ A, const u16* __restrict__ Wt,
        const float* __restrict__ cvec, u16* __restrict__ out, int relu,
        int araw, const int* __restrict__ flag,
        const float* __restrict__ attl, const float* __restrict__ attr,
        float* __restrict__ al, float* __restrict__ ar)
{
    int wave = tid >> 6;
    int lane = tid & 63;
    int m = lane & 15, quad = lane >> 4;
    int row = bid * 64 + wave * 16 + m;
    bool v0 = row < NN;
    bool f32in = araw && flag[0];
    const u16*  Au = (const u16*)A;
    const float* Af = (const float*)A;
    f32x4 acc[8];
#pragma unroll
    for (int j = 0; j < 8; j++) acc[j] = (f32x4){0.f,0.f,0.f,0.f};
#pragma unroll
    for (int t = 0; t < 4; t++){
        bf16x8 a0 = {0,0,0,0,0,0,0,0};
        int kof = t*32 + quad*8;
        if (f32in){
            if (v0){
                const float* p = Af + (size_t)row*FHID + kof;
                float4 u0 = *(const float4*)p, u1 = *(const float4*)(p+4);
                a0[0]=(short)f2bf(u0.x); a0[1]=(short)f2bf(u0.y);
                a0[2]=(short)f2bf(u0.z); a0[3]=(short)f2bf(u0.w);
                a0[4]=(short)f2bf(u1.x); a0[5]=(short)f2bf(u1.y);
                a0[6]=(short)f2bf(u1.z); a0[7]=(short)f2bf(u1.w);
            }
        } else {
            if (v0) a0 = *(const bf16x8*)(Au + (size_t)row*FHID + kof);
        }
#pragma unroll
        for (int ct = 0; ct < 8; ct++){
            bf16x8 wfrag = *(const bf16x8*)(Wt + (ct*16 + m)*FHID + kof);
            acc[ct] = __builtin_amdgcn_mfma_f32_16x16x32_bf16(wfrag, a0, acc[ct], 0, 0, 0);
        }
    }
    bool doa = (attl != nullptr);
    float sl[4] = {0.f,0.f,0.f,0.f};
    float sr[4] = {0.f,0.f,0.f,0.f};
#pragma unroll
    for (int ct = 0; ct < 8; ct++){
        int cb = ct*16 + quad*4;
        float4 cv = *(const float4*)(cvec + cb);
        float w0 = acc[ct][0] + cv.x;
        float w1 = acc[ct][1] + cv.y;
        float w2 = acc[ct][2] + cv.z;
        float w3 = acc[ct][3] + cv.w;
        if (relu){
            w0 = fmaxf(w0, 0.f); w1 = fmaxf(w1, 0.f);
            w2 = fmaxf(w2, 0.f); w3 = fmaxf(w3, 0.f);
        }
        if (doa){
            int h = ct >> 1;
            float4 tl = *(const float4*)(attl + cb);
            float4 tr = *(const float4*)(attr + cb);
            sl[h] += w0*tl.x + w1*tl.y + w2*tl.z + w3*tl.w;
            sr[h] += w0*tr.x + w1*tr.y + w2*tr.z + w3*tr.w;
        }
        if (v0){
            uint2 st; st.x = pack2(w0, w1); st.y = pack2(w2, w3);
            *(uint2*)(out + (size_t)row*FHID + cb) = st;
        }
    }
    if (doa){
#pragma unroll
        for (int h = 0; h < 4; h++){
            sl[h] += __shfl_xor(sl[h], 16, 64);
            sl[h] += __shfl_xor(sl[h], 32, 64);
            sr[h] += __shfl_xor(sr[h], 16, 64);
            sr[h] += __shfl_xor(sr[h], 32, 64);
        }
        if (v0){
            al[row*NHEAD + quad] = sl[quad];
            ar[row*NHEAD + quad] = sr[quad];
        }
    }
}

__global__ __launch_bounds__(256) void gemm128(const void* __restrict__ A,
        const u16* __restrict__ Wt, const float* __restrict__ cvec,
        u16* __restrict__ out, int relu, int araw, const int* __restrict__ flag,
        const float* __restrict__ attl, const float* __restrict__ attr,
        float* __restrict__ al, float* __restrict__ ar)
{
    gemm_body(blockIdx.x, threadIdx.x, A, Wt, cvec, out, relu, araw, flag,
              attl, attr, al, ar);
}

// ---------------- csr body (256 threads) + fused csr∥feature-gemm ------------------
__device__ __forceinline__ void csr_body(int b, int t, const u64* __restrict__ binned,
        const int* __restrict__ gcur, int2* __restrict__ rowdeg, int* __restrict__ colbuf)
{
    __shared__ int deg[BK], ls[BK], cur[BK];
    __shared__ int colstage[CAPB];
    int gb = b * CAPB;
    int cnt = gcur[b];                 // pure count now (zero-based counter)
    if (cnt < 0) cnt = 0;
    if (cnt > CAPB) cnt = CAPB;
    deg[t] = 0;
    __syncthreads();
    for (int i = t; i < cnt; i += 256){
        int d = (int)(binned[gb + i] >> 32);
        atomicAdd(&deg[d & 255], 1);
    }
    __syncthreads();
    ls[t] = deg[t];
    __syncthreads();
    for (int off = 1; off < BK; off <<= 1){
        int x = (t >= off) ? ls[t - off] : 0;
        __syncthreads();
        ls[t] += x;
        __syncthreads();
    }
    int excl = ls[t] - deg[t];
    int node = b*256 + t;
    if (node < NN) rowdeg[node] = (int2){gb + excl, gb + excl + deg[t]};
    cur[t] = excl;
    __syncthreads();
    for (int i = t; i < cnt; i += 256){
        u64 pr = binned[gb + i];
        int d = (int)(pr >> 32) & 255;
        int s = (int)(u32)pr;
        int p = atomicAdd(&cur[d], 1);
        colstage[p] = s;
    }
    __syncthreads();
    for (int i = t; i < cnt; i += 256) colbuf[gb + i] = colstage[i];
}

__global__ __launch_bounds__(256) void csr_gemm(const u64* __restrict__ binned,
        const int* __restrict__ gcur, int2* __restrict__ rowdeg, int* __restrict__ colbuf,
        const void* __restrict__ A, const u16* __restrict__ Wt,
        const float* __restrict__ cvec, u16* __restrict__ out,
        const int* __restrict__ flag)
{
    if (blockIdx.x < NBUCK){
        csr_body(blockIdx.x, threadIdx.x, binned, gcur, rowdeg, colbuf);
    } else {
        gemm_body(blockIdx.x - NBUCK, threadIdx.x, A, Wt, cvec, out, 1, 1, flag,
                  nullptr, nullptr, nullptr, nullptr);
    }
}

// ---------------- SuperGAT conv: ONE NODE PER WAVE (round-6 proven, unchanged) ----
__device__ __forceinline__ void load_e(uint4& X, float& F, int e, int e1,
        const int* __restrict__ colbuf, const u16* __restrict__ hh,
        const float* __restrict__ al, int chbase, int head)
{
    int si = colbuf[e];                 // +64-int slack allocated past BK*CAPB
    bool bad = (e >= e1) || ((u32)si >= NN);
    if (bad) si = 0;
    X = *(const uint4*)(hh + (size_t)si*FHID + chbase);
    float f = al[si*NHEAD + head];
    F = bad ? -1e30f : f;               // masked: pe = exp(-huge) == 0 exactly
}

__device__ __forceinline__ void comp_e(uint4 X, float F,
        const f32x2* hd2, float arn, float& s, f32x2* o2)
{
    f32x2 hs2[4]; unpk8v(X, hs2);
    f32x2 d2 = hd2[0]*hs2[0];
    d2 = hd2[1]*hs2[1] + d2;
    d2 = hd2[2]*hs2[2] + d2;
    d2 = hd2[3]*hs2[3] + d2;
    float lg = quad_red(d2[0] + d2[1]);
    float a2 = (F + arn) * (1.0f / (1.0f + __expf(-lg)));
    a2 = fmaxf(a2, 0.2f*a2);            // leaky_relu(a2, 0.2) for all signs
    float pe = __expf(fminf(a2, 60.f));
    s += pe;
    f32x2 pe2 = (f32x2){pe, pe};
    o2[0] = pe2*hs2[0] + o2[0];
    o2[1] = pe2*hs2[1] + o2[1];
    o2[2] = pe2*hs2[2] + o2[2];
    o2[3] = pe2*hs2[3] + o2[3];
}

__global__ __launch_bounds__(256, 8) void supergat_conv(const u16* __restrict__ hh,
        const float* __restrict__ al, const float* __restrict__ ar,
        const int2* __restrict__ rowdeg, const int* __restrict__ colbuf,
        const float* __restrict__ bias, u16* __restrict__ hout)
{
    int node = (blockIdx.x*256 + threadIdx.x) >> 6;     // one wave per node
    int lane = threadIdx.x & 63;
    int group = lane >> 4;
    int gl    = lane & 15;
    int head  = gl >> 2;
    int chbase = head*32 + (gl & 3)*8;
    if (node >= NN) return;                              // wave-uniform

    uint4 hdv = *(const uint4*)(hh + (size_t)node*FHID + chbase);
    f32x2 hd2[4]; unpk8v(hdv, hd2);
    float arn = ar[node*NHEAD + head];
    float aln = al[node*NHEAD + head];

    // self-loop term (identical in all groups; count it once via group-0 mask)
    f32x2 dd2 = hd2[0]*hd2[0];
    dd2 = hd2[1]*hd2[1] + dd2;
    dd2 = hd2[2]*hd2[2] + dd2;
    dd2 = hd2[3]*hd2[3] + dd2;
    float d = quad_red(dd2[0] + dd2[1]);
    float a = (aln + arn) * (1.0f / (1.0f + __expf(-d)));
    a = fmaxf(a, 0.2f*a);
    float p = __expf(fminf(a, 60.f));
    if (group != 0) p = 0.f;
    float s = p;
    f32x2 p2 = (f32x2){p, p};
    f32x2 o2[4];
    o2[0] = p2*hd2[0];
    o2[1] = p2*hd2[1];
    o2[2] = p2*hd2[2];
    o2[3] = p2*hd2[3];

    int2 rd = rowdeg[node];
    int e0 = rd.x, e1 = rd.y;
    if (e0 < 0) e0 = 0;
    if (e1 > BK*CAPB) e1 = BK*CAPB;
    int it = (e1 - e0 + 3) >> 2;                         // wave-uniform trip count
    int e = e0 + group;

    if (it > 0){
        uint4 xA, xB; float fA, fB;
        load_e(xA, fA, e, e1, colbuf, hh, al, chbase, head);
        e += 4;
        while (true){
            if (it == 1){ comp_e(xA, fA, hd2, arn, s, o2); break; }
            load_e(xB, fB, e, e1, colbuf, hh, al, chbase, head); e += 4;
            comp_e(xA, fA, hd2, arn, s, o2);
            --it;
            if (it == 1){ comp_e(xB, fB, hd2, arn, s, o2); break; }
            load_e(xA, fA, e, e1, colbuf, hh, al, chbase, head); e += 4;
            comp_e(xB, fB, hd2, arn, s, o2);
            --it;
        }
    }

    // combine the 4 groups' partials (same channels, disjoint edge subsets)
    s += __shfl_xor(s, 16, 64);
    s += __shfl_xor(s, 32, 64);
#pragma unroll
    for (int i = 0; i < 4; i++){
        float x0 = o2[i][0], x1 = o2[i][1];
        x0 += __shfl_xor(x0, 16, 64);
        x0 += __shfl_xor(x0, 32, 64);
        x1 += __shfl_xor(x1, 16, 64);
        x1 += __shfl_xor(x1, 32, 64);
        o2[i] = (f32x2){x0, x1};
    }

    if (group == 0){
        float inv = 1.0f / (s + 1e-16f);
        uint4 w;
        w.x = pack2(fmaxf(o2[0][0]*inv + bias[chbase+0], 0.f),
                    fmaxf(o2[0][1]*inv + bias[chbase+1], 0.f));
        w.y = pack2(fmaxf(o2[1][0]*inv + bias[chbase+2], 0.f),
                    fmaxf(o2[1][1]*inv + bias[chbase+3], 0.f));
        w.z = pack2(fmaxf(o2[2][0]*inv + bias[chbase+4], 0.f),
                    fmaxf(o2[2][1]*inv + bias[chbase+5], 0.f));
        w.w = pack2(fmaxf(o2[3][0]*inv + bias[chbase+6], 0.f),
                    fmaxf(o2[3][1]*inv + bias[chbase+7], 0.f));
        *(uint4*)(hout + (size_t)node*FHID + chbase) = w;
    }
}

// ---------------- fused pool + head: one block per graph, 4-way node-parallel ------
// 512 threads: ch = t&127, sub = t>>7. The serial per-node loop (avg ~98 rows) was
// the latency chain at 128 threads; 4 sub-slices stride it 4x, LDS-combine after.
__global__ __launch_bounds__(512) void pool_head(const u16* __restrict__ h,
        const int* __restrict__ batch, const float* __restrict__ hp,
        const int* __restrict__ flag, void* __restrict__ out)
{
    __shared__ int bounds[2];
    __shared__ float part[4][FHID];
    __shared__ float gb[FHID];
    __shared__ float g2[FHID];
    __shared__ float lg[16];
    int gi = blockIdx.x, t = threadIdx.x;
    int ch = t & 127, sub = t >> 7;
    int isf32 = flag[0];
    if (t < 2){
        int target = gi + t;
        int lo = 0, hi = NN;
        while (lo < hi){
            int mid = (lo + hi) >> 1;
            if (batch[mid] < target) lo = mid + 1; else hi = mid;
        }
        bounds[t] = lo;
    }
    __syncthreads();
    float s0 = 0.f, s1 = 0.f;
    int node = bounds[0] + sub, nend = bounds[1];
    for (; node + 4 < nend; node += 8){
        s0 += bf2f(h[(size_t)(node  )*FHID + ch]);
        s1 += bf2f(h[(size_t)(node+4)*FHID + ch]);
    }
    for (; node < nend; node += 4) s0 += bf2f(h[(size_t)node*FHID + ch]);
    part[sub][ch] = s0 + s1;
    __syncthreads();
    const float rs = rsqrtf(1.0f + 1e-5f);
    if (t < FHID){
        float acc0 = (part[0][t] + part[1][t]) + (part[2][t] + part[3][t]);
        gb[t] = acc0 * (hp[17664 + t] * rs) + hp[17792 + t];
    }
    __syncthreads();
    // FC1 4-way split over k
    {
        float acc = 0.f;
        int k0 = sub*32;
        for (int k = k0; k < k0 + 32; k++) acc += gb[k] * hp[k*FHID + ch];
        __syncthreads();               // protect part[] (read above) before overwrite
        part[sub][ch] = acc;
    }
    __syncthreads();
    if (t < FHID){
        float acc = hp[17920 + t] + (part[0][t] + part[1][t]) + (part[2][t] + part[3][t]);
        acc = fmaxf(acc, 0.f);
        g2[t] = acc * (hp[18048 + t] * rs) + hp[18176 + t];
    }
    __syncthreads();
    if (t < NCLS){
        float l = hp[18304 + t];
        for (int k = 0; k < FHID; k++) l += g2[k] * hp[16384 + k*NCLS + t];
        lg[t] = l;
    }
    __syncthreads();
    if (t == 0){
        float mx = lg[0];
        for (int j = 1; j < NCLS; j++) mx = fmaxf(mx, lg[j]);
        float se = 0.f;
        for (int j = 0; j < NCLS; j++) se += __expf(lg[j] - mx);
        float lse = logf(se) + mx;
        if (isf32){
            float* o = (float*)out;
            for (int j = 0; j < NCLS; j++) o[gi*NCLS + j] = lg[j] - lse;
            if (gi == 0) o[NGRAPH*NCLS] = 0.f;
        } else {
            u16* o = (u16*)out;
            for (int j = 0; j < NCLS; j++) o[gi*NCLS + j] = f2bf(lg[j] - lse);
            if (gi == 0) o[NGRAPH*NCLS] = 0;
        }
    }
}

extern "C" void kernel_launch(void* const* d_in, const int* in_sizes, int n_in,
                              void* d_out, int out_size, void* d_ws, size_t ws_size,
                              hipStream_t stream)
{
    (void)in_sizes; (void)n_in; (void)out_size; (void)ws_size;
    const void* x         = d_in[0];
    const int* edge       = (const int*)d_in[1];
    const int* batch      = (const int*)d_in[2];

    char* ws = (char*)d_ws;
    size_t off = 0;
    auto alloc = [&](size_t bytes) -> char* {
        char* p = ws + off; off += (bytes + 255) & ~(size_t)255; return p;
    };
    int*   dflag   = (int*)  alloc(256);
    u16*   WtAll   = (u16*)  alloc((size_t)4*FHID*FHID*2);
    float* cvecAll = (float*)alloc((size_t)4*FHID*4);
    float* biasv   = (float*)alloc((size_t)4*FHID*4);
    float* headp   = (float*)alloc((size_t)19088*4);
    float* al      = (float*)alloc((size_t)NN*NHEAD*4);
    float* ar      = (float*)alloc((size_t)NN*NHEAD*4);
    int*   gcur    = (int*)  alloc((size_t)BK*4);
    int2*  rowdeg  = (int2*) alloc((size_t)NN*8);
    int*   colbuf  = (int*)  alloc((size_t)(BK*CAPB + 64)*4);  // +64 ints: pipeline over-read slack
    u16*   hA      = (u16*)  alloc((size_t)NN*FHID*2);
    u16*   hB      = (u16*)  alloc((size_t)NN*FHID*2);
    // binned (256*6144*8 = 12.58 MB) aliases hB (12.8 MB): hB first written by the
    // attention-layer gemm, strictly after csr_gemm (stream-ordered).
    u64*   binned  = (u64*)hB;

    const int* srcp = edge;
    const int* dstp = edge + EE;

    // zero the per-bucket counters (memset node is graph-capture-legal)
    hipMemsetAsync(gcur, 0, (size_t)BK*4, stream);

    // prep (528 blocks) ∥ bin_edges (391 blocks)
    prep_bin<<<528 + NBLK_E, 256, 0, stream>>>((const u16*)x,
        d_in[5], d_in[6], d_in[3], d_in[4], d_in[9], d_in[7], d_in[8], d_in[12],
        d_in[15], d_in[16], d_in[13], d_in[14], d_in[17], d_in[18], d_in[19], d_in[20],
        d_in[10], d_in[11],
        WtAll, cvecAll, biasv, headp, dflag, srcp, dstp, gcur, binned);

    // build_csr (196 blocks) ∥ feature-layer gemm (782 blocks)
    csr_gemm<<<NBUCK + NBLK_G, 256, 0, stream>>>(binned, gcur, rowdeg, colbuf,
                                                 x, WtAll, cvecAll, hA, dflag);

    for (int i = 0; i < 3; i++){
        gemm128<<<NBLK_G, 256, 0, stream>>>(hA, WtAll + (i+1)*FHID*FHID,
                                            cvecAll + (i+1)*FHID, hB, 0, 0, dflag,
                                            headp + 18320 + i*FHID,
                                            headp + 18704 + i*FHID, al, ar);
        supergat_conv<<<(NN + 3)/4, 256, 0, stream>>>(hB, al, ar, rowdeg, colbuf,
                                                      biasv + (i+1)*FHID, hA);
    }

    pool_head<<<NGRAPH, 512, 0, stream>>>(hA, batch, headp, dflag, d_out);
}